// Round 2
// baseline (5022.648 us; speedup 1.0000x reference)
//
#include <hip/hip_runtime.h>
#include <hip/hip_bf16.h>

// GIN 4-layer forward, round 2: bf16x2-split MFMA GEMMs, fused BN stats,
// binary-search graph counts. chunk stays f32; z0 stored as bf16 hi/lo planes.

typedef __attribute__((ext_vector_type(8))) short bf16x8;
typedef __attribute__((ext_vector_type(4))) float f32x4;

__device__ __forceinline__ unsigned short f2b(float x){
    __hip_bfloat16 h = __float2bfloat16(x);
    return *reinterpret_cast<unsigned short*>(&h);
}
__device__ __forceinline__ float b2f(unsigned short u){
    __hip_bfloat16 h;
    *reinterpret_cast<unsigned short*>(&h) = u;
    return __bfloat162float(h);
}
__device__ __forceinline__ float selu_f(float x){
    const float sc = 1.0507009873554805f, al = 1.6732632423543772f;
    return x > 0.f ? sc * x : sc * al * (__expf(x) - 1.f);
}

// ---------------- CSR build ----------------
__global__ void count_kernel(const int* __restrict__ dst, int* __restrict__ counts, int E){
    int e = blockIdx.x * 256 + threadIdx.x;
    if (e < E) atomicAdd(&counts[dst[e]], 1);
}

__global__ void cnt_bs_kernel(const int* __restrict__ batch, float* __restrict__ cnt, int N){
    __shared__ int sb[257];
    int g = threadIdx.x;
    int lo = 0, hi = N;
    while (lo < hi){ int mid = (lo + hi) >> 1; if (batch[mid] < g) lo = mid + 1; else hi = mid; }
    sb[g] = lo;
    if (g == 0) sb[256] = N;
    __syncthreads();
    cnt[g] = fmaxf((float)(sb[g + 1] - sb[g]), 1.f);
}

__global__ __launch_bounds__(1024) void scan_kernel(const int* __restrict__ counts,
                                                    int* __restrict__ row_ptr, int N){
    __shared__ int wsum[16];
    __shared__ int wpre[16];
    __shared__ int s_total;
    __shared__ int s_running;
    int tid = threadIdx.x;
    int lane = tid & 63, wid = tid >> 6;
    if (tid == 0) s_running = 0;
    __syncthreads();
    for (int base = 0; base < N; base += 4096){
        int idx0 = base + tid * 4;
        int v[4];
        #pragma unroll
        for (int j = 0; j < 4; j++) v[j] = (idx0 + j < N) ? counts[idx0 + j] : 0;
        int tsum = v[0] + v[1] + v[2] + v[3];
        int x = tsum;
        #pragma unroll
        for (int off = 1; off < 64; off <<= 1){
            int y = __shfl_up(x, off, 64);
            if (lane >= off) x += y;
        }
        if (lane == 63) wsum[wid] = x;
        __syncthreads();
        if (wid == 0 && lane < 16){
            int w = wsum[lane];
            int xx = w;
            #pragma unroll
            for (int off = 1; off < 16; off <<= 1){
                int y = __shfl_up(xx, off, 64);
                if (lane >= off) xx += y;
            }
            wpre[lane] = xx - w;
            if (lane == 15) s_total = xx;
        }
        __syncthreads();
        int run = s_running + wpre[wid] + (x - tsum);
        #pragma unroll
        for (int j = 0; j < 4; j++){
            if (idx0 + j < N) row_ptr[idx0 + j] = run;
            run += v[j];
        }
        __syncthreads();
        if (tid == 0) s_running += s_total;
        __syncthreads();
    }
    if (tid == 0) row_ptr[N] = s_running;
}

__global__ void fill_kernel(const int* __restrict__ ei, const int* __restrict__ row_ptr,
                            int* __restrict__ fill, int* __restrict__ colv, int E){
    int e = blockIdx.x * 256 + threadIdx.x;
    if (e < E){
        int s = ei[e];
        int d = ei[E + e];
        int pos = atomicAdd(&fill[d], 1);
        colv[row_ptr[d] + pos] = s;
    }
}

// ------------- weight pre-pack: f32 -> bf16 hi/lo fragments -------------
// dst element index: ((((((l*4+c)*4+kk)*2+wc)*4+nf)*2+plane)*512) + lane*8 + j
__global__ void pack_kernel(const float* __restrict__ W1, const float* __restrict__ W2,
                            unsigned short* __restrict__ W1p, unsigned short* __restrict__ W2p){
    int t = blockIdx.x * 256 + threadIdx.x;   // 65536 total
    int which = t >> 15;
    int u = t & 32767;
    int lane = u & 63; u >>= 6;
    int nf = u & 3; u >>= 2;
    int wc = u & 1; u >>= 1;
    int kk = u & 3; u >>= 2;
    int c = u & 3; u >>= 2;
    int l = u;
    int col = wc * 64 + nf * 16 + (lane & 15);
    int kbase = kk * 32 + (lane >> 4) * 8;
    size_t ob = ((((((size_t)(l * 4 + c) * 4 + kk) * 2 + wc) * 4 + nf) * 2) * 512) + lane * 8;
    unsigned short* dst = which == 0 ? W1p : W2p;
    #pragma unroll
    for (int j = 0; j < 8; j++){
        int k = kbase + j;
        float wv = which == 0 ? W1[((size_t)(l * 512) + c * 128 + col) * 128 + k]
                              : W2[((size_t)(l * 128) + col) * 512 + c * 128 + k];
        unsigned short hi = f2b(wv);
        unsigned short lo = f2b(wv - b2f(hi));
        dst[ob + j] = hi;
        dst[ob + 512 + j] = lo;
    }
}

// ------- GIN aggregation + bf16x2 split: z0 = h + sum neighbors -------
__global__ void agg_split_kernel(const float* __restrict__ h, const int* __restrict__ row_ptr,
                                 const int* __restrict__ colv,
                                 unsigned short* __restrict__ zhi, unsigned short* __restrict__ zlo,
                                 int N){
    int i = blockIdx.x;
    int c = threadIdx.x;
    int p0 = row_ptr[i], p1 = row_ptr[i + 1];
    float acc = h[(size_t)i * 128 + c];
    for (int p = p0; p < p1; p++){
        int s = colv[p];
        acc += h[(size_t)s * 128 + c];
    }
    unsigned short hi = f2b(acc);
    unsigned short lo = f2b(acc - b2f(hi));
    zhi[(size_t)i * 128 + c] = hi;
    zlo[(size_t)i * 128 + c] = lo;
}

// ---------------- GEMM1: chunk = z0 @ W1chunk^T + BN partial stats ----------------
__global__ __launch_bounds__(256) void gemm1_k(
    const unsigned short* __restrict__ Ahi_g, const unsigned short* __restrict__ Alo_g,
    const unsigned short* __restrict__ Bp, float* __restrict__ Cf,
    float* __restrict__ bnpart, int N)
{
    __shared__ __align__(16) unsigned short Ah[128][40];
    __shared__ __align__(16) unsigned short Al[128][40];
    __shared__ float red[2][128][2];
    int tid = threadIdx.x, lane = tid & 63, w = tid >> 6;
    int wr = w >> 1, wc = w & 1;
    int r_lo = lane & 15, kg = lane >> 4;
    int m0 = blockIdx.x * 128;
    int srow = tid >> 1, sseg = tid & 1;
    f32x4 acc[4][4];
    #pragma unroll
    for (int i = 0; i < 4; i++)
        #pragma unroll
        for (int j = 0; j < 4; j++) acc[i][j] = (f32x4){0.f, 0.f, 0.f, 0.f};

    const bf16x8* Bv = reinterpret_cast<const bf16x8*>(Bp);

    for (int kk = 0; kk < 4; kk++){
        __syncthreads();
        int grow = m0 + srow;
        uint4 h0, h1, l0, l1;
        if (grow < N){
            const uint4* ph = reinterpret_cast<const uint4*>(Ahi_g + (size_t)grow * 128 + kk * 32 + sseg * 16);
            const uint4* pl = reinterpret_cast<const uint4*>(Alo_g + (size_t)grow * 128 + kk * 32 + sseg * 16);
            h0 = ph[0]; h1 = ph[1]; l0 = pl[0]; l1 = pl[1];
        } else {
            h0 = h1 = l0 = l1 = make_uint4(0, 0, 0, 0);
        }
        uint4* dh = reinterpret_cast<uint4*>(&Ah[srow][sseg * 16]);
        dh[0] = h0; dh[1] = h1;
        uint4* dl = reinterpret_cast<uint4*>(&Al[srow][sseg * 16]);
        dl[0] = l0; dl[1] = l1;
        __syncthreads();

        bf16x8 bh[4], bl[4];
        #pragma unroll
        for (int nf = 0; nf < 4; nf++){
            int ob = ((kk * 2 + wc) * 4 + nf) * 2;
            bh[nf] = Bv[(ob + 0) * 64 + lane];
            bl[nf] = Bv[(ob + 1) * 64 + lane];
        }
        bf16x8 ah[4], alr[4];
        #pragma unroll
        for (int mf = 0; mf < 4; mf++){
            int ar = wr * 64 + mf * 16 + r_lo;
            ah[mf]  = *reinterpret_cast<const bf16x8*>(&Ah[ar][kg * 8]);
            alr[mf] = *reinterpret_cast<const bf16x8*>(&Al[ar][kg * 8]);
        }
        #pragma unroll
        for (int mf = 0; mf < 4; mf++)
            #pragma unroll
            for (int nf = 0; nf < 4; nf++){
                acc[mf][nf] = __builtin_amdgcn_mfma_f32_16x16x32_bf16(ah[mf],  bh[nf], acc[mf][nf], 0, 0, 0);
                acc[mf][nf] = __builtin_amdgcn_mfma_f32_16x16x32_bf16(ah[mf],  bl[nf], acc[mf][nf], 0, 0, 0);
                acc[mf][nf] = __builtin_amdgcn_mfma_f32_16x16x32_bf16(alr[mf], bh[nf], acc[mf][nf], 0, 0, 0);
            }
    }

    // epilogue: write chunk (f32) + BN column partial sums
    #pragma unroll
    for (int nf = 0; nf < 4; nf++){
        int col = wc * 64 + nf * 16 + r_lo;
        float s = 0.f, q = 0.f;
        #pragma unroll
        for (int mf = 0; mf < 4; mf++)
            #pragma unroll
            for (int r = 0; r < 4; r++){
                int row = m0 + wr * 64 + mf * 16 + kg * 4 + r;
                if (row < N){
                    float v = acc[mf][nf][r];
                    Cf[(size_t)row * 128 + col] = v;
                    s += v; q += v * v;
                }
            }
        s += __shfl_xor(s, 16); s += __shfl_xor(s, 32);
        q += __shfl_xor(q, 16); q += __shfl_xor(q, 32);
        if (kg == 0){ red[wr][col][0] = s; red[wr][col][1] = q; }
    }
    __syncthreads();
    if (tid < 128){
        float s = red[0][tid][0] + red[1][tid][0];
        float q = red[0][tid][1] + red[1][tid][1];
        bnpart[(size_t)blockIdx.x * 256 + tid] = s;
        bnpart[(size_t)blockIdx.x * 256 + 128 + tid] = q;
    }
}

// ------- BN finalize: reduce per-block partials -> scale/shift -------
__global__ void bn_final_k(const float* __restrict__ part, int nb,
                           const float* __restrict__ bng, const float* __restrict__ bnb,
                           float* __restrict__ sc, float* __restrict__ sh,
                           int l, int c0, float invN){
    int col = threadIdx.x;
    float s = 0.f, q = 0.f;
    for (int b = 0; b < nb; b++){
        s += part[(size_t)b * 256 + col];
        q += part[(size_t)b * 256 + 128 + col];
    }
    float mu = s * invN;
    float var = q * invN - mu * mu;
    float inv = rsqrtf(var + 1e-5f);
    float g = bng[l * 512 + c0 + col] * inv;
    sc[col] = g;
    sh[col] = bnb[l * 512 + c0 + col] - mu * g;
}

// ------- GEMM2: z2 (+)= selu(bn(chunk)) @ W2chunk^T -------
__global__ __launch_bounds__(256) void gemm2_k(
    const float* __restrict__ Ch, const unsigned short* __restrict__ Bp,
    float* __restrict__ Z, const float* __restrict__ bsc, const float* __restrict__ bsh,
    const float* __restrict__ b2l, int first, int N)
{
    __shared__ __align__(16) unsigned short Ah[128][40];
    __shared__ __align__(16) unsigned short Al[128][40];
    __shared__ float s_sc[128], s_sh[128];
    int tid = threadIdx.x, lane = tid & 63, w = tid >> 6;
    int wr = w >> 1, wc = w & 1;
    int r_lo = lane & 15, kg = lane >> 4;
    int m0 = blockIdx.x * 128;
    int srow = tid >> 1, sseg = tid & 1;
    if (tid < 128){ s_sc[tid] = bsc[tid]; s_sh[tid] = bsh[tid]; }
    f32x4 acc[4][4];
    #pragma unroll
    for (int i = 0; i < 4; i++)
        #pragma unroll
        for (int j = 0; j < 4; j++) acc[i][j] = (f32x4){0.f, 0.f, 0.f, 0.f};

    const bf16x8* Bv = reinterpret_cast<const bf16x8*>(Bp);

    for (int kk = 0; kk < 4; kk++){
        __syncthreads();
        int grow = m0 + srow;
        float vv[16];
        if (grow < N){
            const float4* pc = reinterpret_cast<const float4*>(Ch + (size_t)grow * 128 + kk * 32 + sseg * 16);
            float4 v0 = pc[0], v1 = pc[1], v2 = pc[2], v3 = pc[3];
            vv[0]=v0.x; vv[1]=v0.y; vv[2]=v0.z; vv[3]=v0.w;
            vv[4]=v1.x; vv[5]=v1.y; vv[6]=v1.z; vv[7]=v1.w;
            vv[8]=v2.x; vv[9]=v2.y; vv[10]=v2.z; vv[11]=v2.w;
            vv[12]=v3.x; vv[13]=v3.y; vv[14]=v3.z; vv[15]=v3.w;
        } else {
            #pragma unroll
            for (int i = 0; i < 16; i++) vv[i] = 0.f;
        }
        union { uint4 u4[2]; unsigned short us[16]; } uh, ul;
        #pragma unroll
        for (int i = 0; i < 16; i++){
            int k = kk * 32 + sseg * 16 + i;
            float t = selu_f(fmaf(vv[i], s_sc[k], s_sh[k]));
            unsigned short hi = f2b(t);
            uh.us[i] = hi;
            ul.us[i] = f2b(t - b2f(hi));
        }
        uint4* dh = reinterpret_cast<uint4*>(&Ah[srow][sseg * 16]);
        dh[0] = uh.u4[0]; dh[1] = uh.u4[1];
        uint4* dl = reinterpret_cast<uint4*>(&Al[srow][sseg * 16]);
        dl[0] = ul.u4[0]; dl[1] = ul.u4[1];
        __syncthreads();

        bf16x8 bh[4], bl[4];
        #pragma unroll
        for (int nf = 0; nf < 4; nf++){
            int ob = ((kk * 2 + wc) * 4 + nf) * 2;
            bh[nf] = Bv[(ob + 0) * 64 + lane];
            bl[nf] = Bv[(ob + 1) * 64 + lane];
        }
        bf16x8 ah[4], alr[4];
        #pragma unroll
        for (int mf = 0; mf < 4; mf++){
            int ar = wr * 64 + mf * 16 + r_lo;
            ah[mf]  = *reinterpret_cast<const bf16x8*>(&Ah[ar][kg * 8]);
            alr[mf] = *reinterpret_cast<const bf16x8*>(&Al[ar][kg * 8]);
        }
        #pragma unroll
        for (int mf = 0; mf < 4; mf++)
            #pragma unroll
            for (int nf = 0; nf < 4; nf++){
                acc[mf][nf] = __builtin_amdgcn_mfma_f32_16x16x32_bf16(ah[mf],  bh[nf], acc[mf][nf], 0, 0, 0);
                acc[mf][nf] = __builtin_amdgcn_mfma_f32_16x16x32_bf16(ah[mf],  bl[nf], acc[mf][nf], 0, 0, 0);
                acc[mf][nf] = __builtin_amdgcn_mfma_f32_16x16x32_bf16(alr[mf], bh[nf], acc[mf][nf], 0, 0, 0);
            }
    }

    #pragma unroll
    for (int nf = 0; nf < 4; nf++){
        int col = wc * 64 + nf * 16 + r_lo;
        #pragma unroll
        for (int mf = 0; mf < 4; mf++)
            #pragma unroll
            for (int r = 0; r < 4; r++){
                int row = m0 + wr * 64 + mf * 16 + kg * 4 + r;
                if (row < N){
                    size_t idx = (size_t)row * 128 + col;
                    float b0 = first ? b2l[col] : Z[idx];
                    Z[idx] = b0 + acc[mf][nf][r];
                }
            }
    }
}

// ---------------- GraphNorm stats (batch sorted) ----------------
__global__ void gn_stats_kernel(const float* __restrict__ z2, const int* __restrict__ batch,
                                float* __restrict__ gsum, float* __restrict__ gsq, int N){
    __shared__ int sb[128];
    int c = threadIdx.x;
    int base = blockIdx.x * 128;
    int end = min(128, N - base);
    if (c < end) sb[c] = batch[base + c];
    __syncthreads();
    float s = 0.f, q = 0.f;
    int run_g = sb[0];
    for (int r = 0; r < end; r++){
        int g = sb[r];
        if (g != run_g){
            atomicAdd(&gsum[run_g * 128 + c], s);
            atomicAdd(&gsq[run_g * 128 + c], q);
            s = 0.f; q = 0.f; run_g = g;
        }
        float v = z2[(size_t)(base + r) * 128 + c];
        s += v; q += v * v;
    }
    atomicAdd(&gsum[run_g * 128 + c], s);
    atomicAdd(&gsq[run_g * 128 + c], q);
}

__global__ void gn_final_kernel(float* __restrict__ gsum, float* __restrict__ gsq,
                                const float* __restrict__ cnt,
                                const float* __restrict__ gng, const float* __restrict__ gnb,
                                const float* __restrict__ gna,
                                float* __restrict__ scale, float* __restrict__ shift, int l){
    int g = blockIdx.x, c = threadIdx.x;
    int idx = g * 128 + c;
    float n = cnt[g];
    float m = gsum[idx] / n;
    float e2 = gsq[idx] / n;
    float a = gna[l * 128 + c];
    float var = e2 - (2.f * a - a * a) * m * m;
    float inv = rsqrtf(var + 1e-5f);
    float sc = gng[l * 128 + c] * inv;
    scale[idx] = sc;
    shift[idx] = gnb[l * 128 + c] - a * m * sc;
    gsum[idx] = 0.f;
    gsq[idx] = 0.f;
}

__global__ void gn_apply_kernel(float* __restrict__ z2h, const int* __restrict__ batch,
                                const float* __restrict__ scale, const float* __restrict__ shift,
                                float* __restrict__ pool, int l, int N){
    __shared__ int sb[128];
    int c = threadIdx.x;
    int base = blockIdx.x * 128;
    int end = min(128, N - base);
    if (c < end) sb[c] = batch[base + c];
    __syncthreads();
    int run_g = sb[0];
    float sc = scale[run_g * 128 + c], sh = shift[run_g * 128 + c];
    float psum = 0.f;
    for (int r = 0; r < end; r++){
        int g = sb[r];
        if (g != run_g){
            atomicAdd(&pool[run_g * 512 + l * 128 + c], psum);
            psum = 0.f; run_g = g;
            sc = scale[g * 128 + c]; sh = shift[g * 128 + c];
        }
        size_t idx = (size_t)(base + r) * 128 + c;
        float v = fmaf(z2h[idx], sc, sh);
        v = selu_f(v);
        z2h[idx] = v;
        psum += v;
    }
    atomicAdd(&pool[run_g * 512 + l * 128 + c], psum);
}

__global__ void final_kernel(const float* __restrict__ pool, const float* __restrict__ cnt,
                             float* __restrict__ out, int n){
    int i = blockIdx.x * 256 + threadIdx.x;
    if (i < n) out[i] = pool[i] / cnt[i >> 9];
}

extern "C" void kernel_launch(void* const* d_in, const int* in_sizes, int n_in,
                              void* d_out, int out_size, void* d_ws, size_t ws_size,
                              hipStream_t stream){
    const float* x    = (const float*)d_in[0];
    const float* W1   = (const float*)d_in[1];
    const float* bng  = (const float*)d_in[2];
    const float* bnb  = (const float*)d_in[3];
    const float* W2   = (const float*)d_in[4];
    const float* b2   = (const float*)d_in[5];
    const float* gng  = (const float*)d_in[6];
    const float* gnb  = (const float*)d_in[7];
    const float* gna  = (const float*)d_in[8];
    const int*   ei   = (const int*)d_in[9];
    const int*   batch= (const int*)d_in[10];
    int N = in_sizes[0] / 128;
    int E = in_sizes[9] / 2;
    float* out = (float*)d_out;
    int RB = (N + 127) / 128;

    char* ws = (char*)d_ws;
    size_t off = 0;
    auto alloc = [&](size_t bytes) -> char* {
        char* p = ws + off;
        off += (bytes + 255) & ~(size_t)255;
        return p;
    };
    unsigned short* z0hi = (unsigned short*)alloc((size_t)N * 128 * 2);
    unsigned short* z0lo = (unsigned short*)alloc((size_t)N * 128 * 2);
    float* chunk  = (float*)alloc((size_t)N * 128 * 4);
    float* z2     = (float*)alloc((size_t)N * 128 * 4);   // doubles as h
    unsigned short* W1p = (unsigned short*)alloc(524288 * 2);
    unsigned short* W2p = (unsigned short*)alloc(524288 * 2);
    int*   row_ptr= (int*)alloc((size_t)(N + 1) * 4);
    int*   colv   = (int*)alloc((size_t)E * 4);
    int*   counts = (int*)alloc((size_t)N * 4);
    int*   fill   = (int*)alloc((size_t)N * 4);
    float* cnt_f  = (float*)alloc(256 * 4);
    float* bnpart = (float*)alloc((size_t)RB * 256 * 4);
    float* bn_sc  = (float*)alloc(128 * 4);
    float* bn_sh  = (float*)alloc(128 * 4);
    float* gn_sum = (float*)alloc(256 * 128 * 4);  // contiguous with gn_sq
    float* gn_sq  = (float*)alloc(256 * 128 * 4);
    float* gn_sc  = (float*)alloc(256 * 128 * 4);
    float* gn_sh  = (float*)alloc(256 * 128 * 4);
    float* pool   = (float*)alloc(256 * 512 * 4);
    (void)ws_size;

    hipMemsetAsync(counts, 0, (size_t)N * 4, stream);
    hipMemsetAsync(fill,   0, (size_t)N * 4, stream);
    hipMemsetAsync(gn_sum, 0, 2 * 256 * 128 * 4, stream);      // gn_sum + gn_sq
    hipMemsetAsync(pool,   0, 256 * 512 * 4, stream);

    pack_kernel<<<256, 256, 0, stream>>>(W1, W2, W1p, W2p);
    count_kernel<<<(E + 255) / 256, 256, 0, stream>>>(ei + E, counts, E);
    scan_kernel<<<1, 1024, 0, stream>>>(counts, row_ptr, N);
    fill_kernel<<<(E + 255) / 256, 256, 0, stream>>>(ei, row_ptr, fill, colv, E);
    cnt_bs_kernel<<<1, 256, 0, stream>>>(batch, cnt_f, N);

    const float* hcur = x;
    for (int l = 0; l < 4; l++){
        agg_split_kernel<<<N, 128, 0, stream>>>(hcur, row_ptr, colv, z0hi, z0lo, N);
        for (int c = 0; c < 4; c++){
            const unsigned short* B1 = W1p + (size_t)(l * 4 + c) * 32768;
            gemm1_k<<<RB, 256, 0, stream>>>(z0hi, z0lo, B1, chunk, bnpart, N);
            bn_final_k<<<1, 128, 0, stream>>>(bnpart, RB, bng, bnb, bn_sc, bn_sh,
                                              l, c * 128, 1.f / (float)N);
            const unsigned short* B2 = W2p + (size_t)(l * 4 + c) * 32768;
            gemm2_k<<<RB, 256, 0, stream>>>(chunk, B2, z2, bn_sc, bn_sh,
                                            b2 + l * 128, (c == 0) ? 1 : 0, N);
        }
        gn_stats_kernel<<<RB, 128, 0, stream>>>(z2, batch, gn_sum, gn_sq, N);
        gn_final_kernel<<<256, 128, 0, stream>>>(gn_sum, gn_sq, cnt_f, gng, gnb, gna,
                                                 gn_sc, gn_sh, l);
        gn_apply_kernel<<<RB, 128, 0, stream>>>(z2, batch, gn_sc, gn_sh, pool, l, N);
        hcur = z2;
    }
    final_kernel<<<(out_size + 255) / 256, 256, 0, stream>>>(pool, cnt_f, out, out_size);
}

// Round 3
// 2318.596 us; speedup vs baseline: 2.1662x; 2.1662x over previous
//
#include <hip/hip_runtime.h>
#include <hip/hip_bf16.h>

// GIN 4-layer forward, round 3: bf16x2-split MFMA GEMMs, BN stats via
// epilogue atomics (fixes 187us-per-launch serial bn_final), CSR agg.

typedef __attribute__((ext_vector_type(8))) short bf16x8;
typedef __attribute__((ext_vector_type(4))) float f32x4;

__device__ __forceinline__ unsigned short f2b(float x){
    __hip_bfloat16 h = __float2bfloat16(x);
    return *reinterpret_cast<unsigned short*>(&h);
}
__device__ __forceinline__ float b2f(unsigned short u){
    __hip_bfloat16 h;
    *reinterpret_cast<unsigned short*>(&h) = u;
    return __bfloat162float(h);
}
__device__ __forceinline__ float selu_f(float x){
    const float sc = 1.0507009873554805f, al = 1.6732632423543772f;
    return x > 0.f ? sc * x : sc * al * (__expf(x) - 1.f);
}

// ---------------- CSR build ----------------
__global__ void count_kernel(const int* __restrict__ dst, int* __restrict__ counts, int E){
    int e = blockIdx.x * 256 + threadIdx.x;
    if (e < E) atomicAdd(&counts[dst[e]], 1);
}

__global__ void cnt_bs_kernel(const int* __restrict__ batch, float* __restrict__ cnt, int N){
    __shared__ int sb[257];
    int g = threadIdx.x;
    int lo = 0, hi = N;
    while (lo < hi){ int mid = (lo + hi) >> 1; if (batch[mid] < g) lo = mid + 1; else hi = mid; }
    sb[g] = lo;
    if (g == 0) sb[256] = N;
    __syncthreads();
    cnt[g] = fmaxf((float)(sb[g + 1] - sb[g]), 1.f);
}

__global__ __launch_bounds__(1024) void scan_kernel(const int* __restrict__ counts,
                                                    int* __restrict__ row_ptr, int N){
    __shared__ int wsum[16];
    __shared__ int wpre[16];
    __shared__ int s_total;
    __shared__ int s_running;
    int tid = threadIdx.x;
    int lane = tid & 63, wid = tid >> 6;
    if (tid == 0) s_running = 0;
    __syncthreads();
    for (int base = 0; base < N; base += 4096){
        int idx0 = base + tid * 4;
        int v[4];
        #pragma unroll
        for (int j = 0; j < 4; j++) v[j] = (idx0 + j < N) ? counts[idx0 + j] : 0;
        int tsum = v[0] + v[1] + v[2] + v[3];
        int x = tsum;
        #pragma unroll
        for (int off = 1; off < 64; off <<= 1){
            int y = __shfl_up(x, off, 64);
            if (lane >= off) x += y;
        }
        if (lane == 63) wsum[wid] = x;
        __syncthreads();
        if (wid == 0 && lane < 16){
            int w = wsum[lane];
            int xx = w;
            #pragma unroll
            for (int off = 1; off < 16; off <<= 1){
                int y = __shfl_up(xx, off, 64);
                if (lane >= off) xx += y;
            }
            wpre[lane] = xx - w;
            if (lane == 15) s_total = xx;
        }
        __syncthreads();
        int run = s_running + wpre[wid] + (x - tsum);
        #pragma unroll
        for (int j = 0; j < 4; j++){
            if (idx0 + j < N) row_ptr[idx0 + j] = run;
            run += v[j];
        }
        __syncthreads();
        if (tid == 0) s_running += s_total;
        __syncthreads();
    }
    if (tid == 0) row_ptr[N] = s_running;
}

__global__ void fill_kernel(const int* __restrict__ ei, const int* __restrict__ row_ptr,
                            int* __restrict__ fill, int* __restrict__ colv, int E){
    int e = blockIdx.x * 256 + threadIdx.x;
    if (e < E){
        int s = ei[e];
        int d = ei[E + e];
        int pos = atomicAdd(&fill[d], 1);
        colv[row_ptr[d] + pos] = s;
    }
}

// ------------- weight pre-pack: f32 -> bf16 hi/lo fragments -------------
__global__ void pack_kernel(const float* __restrict__ W1, const float* __restrict__ W2,
                            unsigned short* __restrict__ W1p, unsigned short* __restrict__ W2p){
    int t = blockIdx.x * 256 + threadIdx.x;   // 65536 total
    int which = t >> 15;
    int u = t & 32767;
    int lane = u & 63; u >>= 6;
    int nf = u & 3; u >>= 2;
    int wc = u & 1; u >>= 1;
    int kk = u & 3; u >>= 2;
    int c = u & 3; u >>= 2;
    int l = u;
    int col = wc * 64 + nf * 16 + (lane & 15);
    int kbase = kk * 32 + (lane >> 4) * 8;
    size_t ob = ((((((size_t)(l * 4 + c) * 4 + kk) * 2 + wc) * 4 + nf) * 2) * 512) + lane * 8;
    unsigned short* dst = which == 0 ? W1p : W2p;
    #pragma unroll
    for (int j = 0; j < 8; j++){
        int k = kbase + j;
        float wv = which == 0 ? W1[((size_t)(l * 512) + c * 128 + col) * 128 + k]
                              : W2[((size_t)(l * 128) + col) * 512 + c * 128 + k];
        unsigned short hi = f2b(wv);
        unsigned short lo = f2b(wv - b2f(hi));
        dst[ob + j] = hi;
        dst[ob + 512 + j] = lo;
    }
}

// ------- GIN aggregation + bf16x2 split: z0 = h + sum neighbors -------
__global__ void agg_split_kernel(const float* __restrict__ h, const int* __restrict__ row_ptr,
                                 const int* __restrict__ colv,
                                 unsigned short* __restrict__ zhi, unsigned short* __restrict__ zlo,
                                 int N){
    int i = blockIdx.x;
    int c = threadIdx.x;
    int p0 = row_ptr[i], p1 = row_ptr[i + 1];
    float acc = h[(size_t)i * 128 + c];
    for (int p = p0; p < p1; p++){
        int s = colv[p];
        acc += h[(size_t)s * 128 + c];
    }
    unsigned short hi = f2b(acc);
    unsigned short lo = f2b(acc - b2f(hi));
    zhi[(size_t)i * 128 + c] = hi;
    zlo[(size_t)i * 128 + c] = lo;
}

// ---------------- GEMM1: chunk = z0 @ W1chunk^T + BN stats via atomics ----------------
__global__ __launch_bounds__(256) void gemm1_k(
    const unsigned short* __restrict__ Ahi_g, const unsigned short* __restrict__ Alo_g,
    const unsigned short* __restrict__ Bp, float* __restrict__ Cf,
    float* __restrict__ bn_acc, int N)
{
    __shared__ __align__(16) unsigned short Ah[128][40];
    __shared__ __align__(16) unsigned short Al[128][40];
    __shared__ float red[2][128][2];
    int tid = threadIdx.x, lane = tid & 63, w = tid >> 6;
    int wr = w >> 1, wc = w & 1;
    int r_lo = lane & 15, kg = lane >> 4;
    int m0 = blockIdx.x * 128;
    int srow = tid >> 1, sseg = tid & 1;
    f32x4 acc[4][4];
    #pragma unroll
    for (int i = 0; i < 4; i++)
        #pragma unroll
        for (int j = 0; j < 4; j++) acc[i][j] = (f32x4){0.f, 0.f, 0.f, 0.f};

    const bf16x8* Bv = reinterpret_cast<const bf16x8*>(Bp);

    for (int kk = 0; kk < 4; kk++){
        __syncthreads();
        int grow = m0 + srow;
        uint4 h0, h1, l0, l1;
        if (grow < N){
            const uint4* ph = reinterpret_cast<const uint4*>(Ahi_g + (size_t)grow * 128 + kk * 32 + sseg * 16);
            const uint4* pl = reinterpret_cast<const uint4*>(Alo_g + (size_t)grow * 128 + kk * 32 + sseg * 16);
            h0 = ph[0]; h1 = ph[1]; l0 = pl[0]; l1 = pl[1];
        } else {
            h0 = h1 = l0 = l1 = make_uint4(0, 0, 0, 0);
        }
        uint4* dh = reinterpret_cast<uint4*>(&Ah[srow][sseg * 16]);
        dh[0] = h0; dh[1] = h1;
        uint4* dl = reinterpret_cast<uint4*>(&Al[srow][sseg * 16]);
        dl[0] = l0; dl[1] = l1;
        __syncthreads();

        bf16x8 bh[4], bl[4];
        #pragma unroll
        for (int nf = 0; nf < 4; nf++){
            int ob = ((kk * 2 + wc) * 4 + nf) * 2;
            bh[nf] = Bv[(ob + 0) * 64 + lane];
            bl[nf] = Bv[(ob + 1) * 64 + lane];
        }
        bf16x8 ah[4], alr[4];
        #pragma unroll
        for (int mf = 0; mf < 4; mf++){
            int ar = wr * 64 + mf * 16 + r_lo;
            ah[mf]  = *reinterpret_cast<const bf16x8*>(&Ah[ar][kg * 8]);
            alr[mf] = *reinterpret_cast<const bf16x8*>(&Al[ar][kg * 8]);
        }
        #pragma unroll
        for (int mf = 0; mf < 4; mf++)
            #pragma unroll
            for (int nf = 0; nf < 4; nf++){
                acc[mf][nf] = __builtin_amdgcn_mfma_f32_16x16x32_bf16(ah[mf],  bh[nf], acc[mf][nf], 0, 0, 0);
                acc[mf][nf] = __builtin_amdgcn_mfma_f32_16x16x32_bf16(ah[mf],  bl[nf], acc[mf][nf], 0, 0, 0);
                acc[mf][nf] = __builtin_amdgcn_mfma_f32_16x16x32_bf16(alr[mf], bh[nf], acc[mf][nf], 0, 0, 0);
            }
    }

    // epilogue: write chunk (f32) + BN column sums -> global atomics
    #pragma unroll
    for (int nf = 0; nf < 4; nf++){
        int col = wc * 64 + nf * 16 + r_lo;
        float s = 0.f, q = 0.f;
        #pragma unroll
        for (int mf = 0; mf < 4; mf++)
            #pragma unroll
            for (int r = 0; r < 4; r++){
                int row = m0 + wr * 64 + mf * 16 + kg * 4 + r;
                if (row < N){
                    float v = acc[mf][nf][r];
                    Cf[(size_t)row * 128 + col] = v;
                    s += v; q += v * v;
                }
            }
        s += __shfl_xor(s, 16); s += __shfl_xor(s, 32);
        q += __shfl_xor(q, 16); q += __shfl_xor(q, 32);
        if (kg == 0){ red[wr][col][0] = s; red[wr][col][1] = q; }
    }
    __syncthreads();
    if (tid < 128){
        atomicAdd(&bn_acc[tid],       red[0][tid][0] + red[1][tid][0]);
        atomicAdd(&bn_acc[128 + tid], red[0][tid][1] + red[1][tid][1]);
    }
}

// ------- BN finalize: 256-float read -> scale/shift -------
__global__ void bn_final_k(const float* __restrict__ bn_acc,
                           const float* __restrict__ bng, const float* __restrict__ bnb,
                           float* __restrict__ sc, float* __restrict__ sh,
                           int l, int c0, float invN){
    int col = threadIdx.x;
    float s = bn_acc[col];
    float q = bn_acc[128 + col];
    float mu = s * invN;
    float var = q * invN - mu * mu;
    float inv = rsqrtf(var + 1e-5f);
    float g = bng[l * 512 + c0 + col] * inv;
    sc[col] = g;
    sh[col] = bnb[l * 512 + c0 + col] - mu * g;
}

// ------- GEMM2: z2 (+)= selu(bn(chunk)) @ W2chunk^T -------
__global__ __launch_bounds__(256) void gemm2_k(
    const float* __restrict__ Ch, const unsigned short* __restrict__ Bp,
    float* __restrict__ Z, const float* __restrict__ bsc, const float* __restrict__ bsh,
    const float* __restrict__ b2l, int first, int N)
{
    __shared__ __align__(16) unsigned short Ah[128][40];
    __shared__ __align__(16) unsigned short Al[128][40];
    __shared__ float s_sc[128], s_sh[128];
    int tid = threadIdx.x, lane = tid & 63, w = tid >> 6;
    int wr = w >> 1, wc = w & 1;
    int r_lo = lane & 15, kg = lane >> 4;
    int m0 = blockIdx.x * 128;
    int srow = tid >> 1, sseg = tid & 1;
    if (tid < 128){ s_sc[tid] = bsc[tid]; s_sh[tid] = bsh[tid]; }
    f32x4 acc[4][4];
    #pragma unroll
    for (int i = 0; i < 4; i++)
        #pragma unroll
        for (int j = 0; j < 4; j++) acc[i][j] = (f32x4){0.f, 0.f, 0.f, 0.f};

    const bf16x8* Bv = reinterpret_cast<const bf16x8*>(Bp);

    for (int kk = 0; kk < 4; kk++){
        __syncthreads();
        int grow = m0 + srow;
        float vv[16];
        if (grow < N){
            const float4* pc = reinterpret_cast<const float4*>(Ch + (size_t)grow * 128 + kk * 32 + sseg * 16);
            float4 v0 = pc[0], v1 = pc[1], v2 = pc[2], v3 = pc[3];
            vv[0]=v0.x; vv[1]=v0.y; vv[2]=v0.z; vv[3]=v0.w;
            vv[4]=v1.x; vv[5]=v1.y; vv[6]=v1.z; vv[7]=v1.w;
            vv[8]=v2.x; vv[9]=v2.y; vv[10]=v2.z; vv[11]=v2.w;
            vv[12]=v3.x; vv[13]=v3.y; vv[14]=v3.z; vv[15]=v3.w;
        } else {
            #pragma unroll
            for (int i = 0; i < 16; i++) vv[i] = 0.f;
        }
        union { uint4 u4[2]; unsigned short us[16]; } uh, ul;
        #pragma unroll
        for (int i = 0; i < 16; i++){
            int k = kk * 32 + sseg * 16 + i;
            float t = selu_f(fmaf(vv[i], s_sc[k], s_sh[k]));
            unsigned short hi = f2b(t);
            uh.us[i] = hi;
            ul.us[i] = f2b(t - b2f(hi));
        }
        uint4* dh = reinterpret_cast<uint4*>(&Ah[srow][sseg * 16]);
        dh[0] = uh.u4[0]; dh[1] = uh.u4[1];
        uint4* dl = reinterpret_cast<uint4*>(&Al[srow][sseg * 16]);
        dl[0] = ul.u4[0]; dl[1] = ul.u4[1];
        __syncthreads();

        bf16x8 bh[4], bl[4];
        #pragma unroll
        for (int nf = 0; nf < 4; nf++){
            int ob = ((kk * 2 + wc) * 4 + nf) * 2;
            bh[nf] = Bv[(ob + 0) * 64 + lane];
            bl[nf] = Bv[(ob + 1) * 64 + lane];
        }
        bf16x8 ah[4], alr[4];
        #pragma unroll
        for (int mf = 0; mf < 4; mf++){
            int ar = wr * 64 + mf * 16 + r_lo;
            ah[mf]  = *reinterpret_cast<const bf16x8*>(&Ah[ar][kg * 8]);
            alr[mf] = *reinterpret_cast<const bf16x8*>(&Al[ar][kg * 8]);
        }
        #pragma unroll
        for (int mf = 0; mf < 4; mf++)
            #pragma unroll
            for (int nf = 0; nf < 4; nf++){
                acc[mf][nf] = __builtin_amdgcn_mfma_f32_16x16x32_bf16(ah[mf],  bh[nf], acc[mf][nf], 0, 0, 0);
                acc[mf][nf] = __builtin_amdgcn_mfma_f32_16x16x32_bf16(ah[mf],  bl[nf], acc[mf][nf], 0, 0, 0);
                acc[mf][nf] = __builtin_amdgcn_mfma_f32_16x16x32_bf16(alr[mf], bh[nf], acc[mf][nf], 0, 0, 0);
            }
    }

    #pragma unroll
    for (int nf = 0; nf < 4; nf++){
        int col = wc * 64 + nf * 16 + r_lo;
        #pragma unroll
        for (int mf = 0; mf < 4; mf++)
            #pragma unroll
            for (int r = 0; r < 4; r++){
                int row = m0 + wr * 64 + mf * 16 + kg * 4 + r;
                if (row < N){
                    size_t idx = (size_t)row * 128 + col;
                    float b0 = first ? b2l[col] : Z[idx];
                    Z[idx] = b0 + acc[mf][nf][r];
                }
            }
    }
}

// ---------------- GraphNorm stats (batch sorted) ----------------
__global__ void gn_stats_kernel(const float* __restrict__ z2, const int* __restrict__ batch,
                                float* __restrict__ gsum, float* __restrict__ gsq, int N){
    __shared__ int sb[128];
    int c = threadIdx.x;
    int base = blockIdx.x * 128;
    int end = min(128, N - base);
    if (c < end) sb[c] = batch[base + c];
    __syncthreads();
    float s = 0.f, q = 0.f;
    int run_g = sb[0];
    for (int r = 0; r < end; r++){
        int g = sb[r];
        if (g != run_g){
            atomicAdd(&gsum[run_g * 128 + c], s);
            atomicAdd(&gsq[run_g * 128 + c], q);
            s = 0.f; q = 0.f; run_g = g;
        }
        float v = z2[(size_t)(base + r) * 128 + c];
        s += v; q += v * v;
    }
    atomicAdd(&gsum[run_g * 128 + c], s);
    atomicAdd(&gsq[run_g * 128 + c], q);
}

__global__ void gn_final_kernel(float* __restrict__ gsum, float* __restrict__ gsq,
                                const float* __restrict__ cnt,
                                const float* __restrict__ gng, const float* __restrict__ gnb,
                                const float* __restrict__ gna,
                                float* __restrict__ scale, float* __restrict__ shift, int l){
    int g = blockIdx.x, c = threadIdx.x;
    int idx = g * 128 + c;
    float n = cnt[g];
    float m = gsum[idx] / n;
    float e2 = gsq[idx] / n;
    float a = gna[l * 128 + c];
    float var = e2 - (2.f * a - a * a) * m * m;
    float inv = rsqrtf(var + 1e-5f);
    float sc = gng[l * 128 + c] * inv;
    scale[idx] = sc;
    shift[idx] = gnb[l * 128 + c] - a * m * sc;
    gsum[idx] = 0.f;
    gsq[idx] = 0.f;
}

__global__ void gn_apply_kernel(float* __restrict__ z2h, const int* __restrict__ batch,
                                const float* __restrict__ scale, const float* __restrict__ shift,
                                float* __restrict__ pool, int l, int N){
    __shared__ int sb[128];
    int c = threadIdx.x;
    int base = blockIdx.x * 128;
    int end = min(128, N - base);
    if (c < end) sb[c] = batch[base + c];
    __syncthreads();
    int run_g = sb[0];
    float sc = scale[run_g * 128 + c], sh = shift[run_g * 128 + c];
    float psum = 0.f;
    for (int r = 0; r < end; r++){
        int g = sb[r];
        if (g != run_g){
            atomicAdd(&pool[run_g * 512 + l * 128 + c], psum);
            psum = 0.f; run_g = g;
            sc = scale[g * 128 + c]; sh = shift[g * 128 + c];
        }
        size_t idx = (size_t)(base + r) * 128 + c;
        float v = fmaf(z2h[idx], sc, sh);
        v = selu_f(v);
        z2h[idx] = v;
        psum += v;
    }
    atomicAdd(&pool[run_g * 512 + l * 128 + c], psum);
}

__global__ void final_kernel(const float* __restrict__ pool, const float* __restrict__ cnt,
                             float* __restrict__ out, int n){
    int i = blockIdx.x * 256 + threadIdx.x;
    if (i < n) out[i] = pool[i] / cnt[i >> 9];
}

extern "C" void kernel_launch(void* const* d_in, const int* in_sizes, int n_in,
                              void* d_out, int out_size, void* d_ws, size_t ws_size,
                              hipStream_t stream){
    const float* x    = (const float*)d_in[0];
    const float* W1   = (const float*)d_in[1];
    const float* bng  = (const float*)d_in[2];
    const float* bnb  = (const float*)d_in[3];
    const float* W2   = (const float*)d_in[4];
    const float* b2   = (const float*)d_in[5];
    const float* gng  = (const float*)d_in[6];
    const float* gnb  = (const float*)d_in[7];
    const float* gna  = (const float*)d_in[8];
    const int*   ei   = (const int*)d_in[9];
    const int*   batch= (const int*)d_in[10];
    int N = in_sizes[0] / 128;
    int E = in_sizes[9] / 2;
    float* out = (float*)d_out;
    int RB = (N + 127) / 128;

    char* ws = (char*)d_ws;
    size_t off = 0;
    auto alloc = [&](size_t bytes) -> char* {
        char* p = ws + off;
        off += (bytes + 255) & ~(size_t)255;
        return p;
    };
    unsigned short* z0hi = (unsigned short*)alloc((size_t)N * 128 * 2);
    unsigned short* z0lo = (unsigned short*)alloc((size_t)N * 128 * 2);
    float* chunk  = (float*)alloc((size_t)N * 128 * 4);
    float* z2     = (float*)alloc((size_t)N * 128 * 4);   // doubles as h
    unsigned short* W1p = (unsigned short*)alloc(524288 * 2);
    unsigned short* W2p = (unsigned short*)alloc(524288 * 2);
    int*   row_ptr= (int*)alloc((size_t)(N + 1) * 4);
    int*   colv   = (int*)alloc((size_t)E * 4);
    int*   counts = (int*)alloc((size_t)N * 4);
    int*   fill   = (int*)alloc((size_t)N * 4);
    float* cnt_f  = (float*)alloc(256 * 4);
    float* bn_acc = (float*)alloc(16 * 256 * 4);   // [l*4+c][256] sum|sq
    float* bn_sc  = (float*)alloc(128 * 4);
    float* bn_sh  = (float*)alloc(128 * 4);
    float* gn_sum = (float*)alloc(256 * 128 * 4);  // contiguous with gn_sq
    float* gn_sq  = (float*)alloc(256 * 128 * 4);
    float* gn_sc  = (float*)alloc(256 * 128 * 4);
    float* gn_sh  = (float*)alloc(256 * 128 * 4);
    float* pool   = (float*)alloc(256 * 512 * 4);
    (void)ws_size;

    hipMemsetAsync(counts, 0, (size_t)N * 4, stream);
    hipMemsetAsync(fill,   0, (size_t)N * 4, stream);
    hipMemsetAsync(bn_acc, 0, 16 * 256 * 4, stream);
    hipMemsetAsync(gn_sum, 0, 2 * 256 * 128 * 4, stream);      // gn_sum + gn_sq
    hipMemsetAsync(pool,   0, 256 * 512 * 4, stream);

    pack_kernel<<<256, 256, 0, stream>>>(W1, W2, W1p, W2p);
    count_kernel<<<(E + 255) / 256, 256, 0, stream>>>(ei + E, counts, E);
    scan_kernel<<<1, 1024, 0, stream>>>(counts, row_ptr, N);
    fill_kernel<<<(E + 255) / 256, 256, 0, stream>>>(ei, row_ptr, fill, colv, E);
    cnt_bs_kernel<<<1, 256, 0, stream>>>(batch, cnt_f, N);

    const float* hcur = x;
    for (int l = 0; l < 4; l++){
        agg_split_kernel<<<N, 128, 0, stream>>>(hcur, row_ptr, colv, z0hi, z0lo, N);
        for (int c = 0; c < 4; c++){
            const unsigned short* B1 = W1p + (size_t)(l * 4 + c) * 32768;
            gemm1_k<<<RB, 256, 0, stream>>>(z0hi, z0lo, B1, chunk,
                                            bn_acc + (l * 4 + c) * 256, N);
            bn_final_k<<<1, 128, 0, stream>>>(bn_acc + (l * 4 + c) * 256, bng, bnb,
                                              bn_sc, bn_sh, l, c * 128, 1.f / (float)N);
            const unsigned short* B2 = W2p + (size_t)(l * 4 + c) * 32768;
            gemm2_k<<<RB, 256, 0, stream>>>(chunk, B2, z2, bn_sc, bn_sh,
                                            b2 + l * 128, (c == 0) ? 1 : 0, N);
        }
        gn_stats_kernel<<<RB, 128, 0, stream>>>(z2, batch, gn_sum, gn_sq, N);
        gn_final_kernel<<<256, 128, 0, stream>>>(gn_sum, gn_sq, cnt_f, gng, gnb, gna,
                                                 gn_sc, gn_sh, l);
        gn_apply_kernel<<<RB, 128, 0, stream>>>(z2, batch, gn_sc, gn_sh, pool, l, N);
        hcur = z2;
    }
    final_kernel<<<(out_size + 255) / 256, 256, 0, stream>>>(pool, cnt_f, out, out_size);
}

// Round 5
// 1941.499 us; speedup vs baseline: 2.5870x; 1.1942x over previous
//
#include <hip/hip_runtime.h>
#include <hip/hip_bf16.h>

// GIN 4-layer forward, round 5: fix r4's LDS staging bug (uint4 = 8 shorts,
// not 16), ws-adaptive z1 chunk width. One gemm1/gemm2 dispatch per layer
// when z1 fits, MLP-unrolled float4 gather, bf16x2-split MFMA.

typedef __attribute__((ext_vector_type(8))) short bf16x8;
typedef __attribute__((ext_vector_type(4))) float f32x4;

__device__ __forceinline__ unsigned short f2b(float x){
    __hip_bfloat16 h = __float2bfloat16(x);
    return *reinterpret_cast<unsigned short*>(&h);
}
__device__ __forceinline__ float b2f(unsigned short u){
    __hip_bfloat16 h;
    *reinterpret_cast<unsigned short*>(&h) = u;
    return __bfloat162float(h);
}
__device__ __forceinline__ float selu_f(float x){
    const float sc = 1.0507009873554805f, al = 1.6732632423543772f;
    return x > 0.f ? sc * x : sc * al * (__expf(x) - 1.f);
}

// ---------------- CSR build ----------------
__global__ void count_kernel(const int* __restrict__ dst, int* __restrict__ counts, int E){
    int e = blockIdx.x * 256 + threadIdx.x;
    if (e < E) atomicAdd(&counts[dst[e]], 1);
}

__global__ void cnt_bs_kernel(const int* __restrict__ batch, float* __restrict__ cnt, int N){
    __shared__ int sb[257];
    int g = threadIdx.x;
    int lo = 0, hi = N;
    while (lo < hi){ int mid = (lo + hi) >> 1; if (batch[mid] < g) lo = mid + 1; else hi = mid; }
    sb[g] = lo;
    if (g == 0) sb[256] = N;
    __syncthreads();
    cnt[g] = fmaxf((float)(sb[g + 1] - sb[g]), 1.f);
}

__global__ __launch_bounds__(1024) void scan_kernel(const int* __restrict__ counts,
                                                    int* __restrict__ row_ptr, int N){
    __shared__ int wsum[16];
    __shared__ int wpre[16];
    __shared__ int s_total;
    __shared__ int s_running;
    int tid = threadIdx.x;
    int lane = tid & 63, wid = tid >> 6;
    if (tid == 0) s_running = 0;
    __syncthreads();
    for (int base = 0; base < N; base += 4096){
        int idx0 = base + tid * 4;
        int v[4];
        #pragma unroll
        for (int j = 0; j < 4; j++) v[j] = (idx0 + j < N) ? counts[idx0 + j] : 0;
        int tsum = v[0] + v[1] + v[2] + v[3];
        int x = tsum;
        #pragma unroll
        for (int off = 1; off < 64; off <<= 1){
            int y = __shfl_up(x, off, 64);
            if (lane >= off) x += y;
        }
        if (lane == 63) wsum[wid] = x;
        __syncthreads();
        if (wid == 0 && lane < 16){
            int w = wsum[lane];
            int xx = w;
            #pragma unroll
            for (int off = 1; off < 16; off <<= 1){
                int y = __shfl_up(xx, off, 64);
                if (lane >= off) xx += y;
            }
            wpre[lane] = xx - w;
            if (lane == 15) s_total = xx;
        }
        __syncthreads();
        int run = s_running + wpre[wid] + (x - tsum);
        #pragma unroll
        for (int j = 0; j < 4; j++){
            if (idx0 + j < N) row_ptr[idx0 + j] = run;
            run += v[j];
        }
        __syncthreads();
        if (tid == 0) s_running += s_total;
        __syncthreads();
    }
    if (tid == 0) row_ptr[N] = s_running;
}

__global__ void fill_kernel(const int* __restrict__ ei, const int* __restrict__ row_ptr,
                            int* __restrict__ fill, int* __restrict__ colv, int E){
    int e = blockIdx.x * 256 + threadIdx.x;
    if (e < E){
        int s = ei[e];
        int d = ei[E + e];
        int pos = atomicAdd(&fill[d], 1);
        colv[row_ptr[d] + pos] = s;
    }
}

// ------------- weight pre-pack: f32 -> bf16 hi/lo fragments -------------
__global__ void pack_kernel(const float* __restrict__ W1, const float* __restrict__ W2,
                            unsigned short* __restrict__ W1p, unsigned short* __restrict__ W2p){
    int t = blockIdx.x * 256 + threadIdx.x;   // 65536 total
    int which = t >> 15;
    int u = t & 32767;
    int lane = u & 63; u >>= 6;
    int nf = u & 3; u >>= 2;
    int wc = u & 1; u >>= 1;
    int kk = u & 3; u >>= 2;
    int c = u & 3; u >>= 2;
    int l = u;
    int col = wc * 64 + nf * 16 + (lane & 15);
    int kbase = kk * 32 + (lane >> 4) * 8;
    size_t ob = ((((((size_t)(l * 4 + c) * 4 + kk) * 2 + wc) * 4 + nf) * 2) * 512) + lane * 8;
    unsigned short* dst = which == 0 ? W1p : W2p;
    #pragma unroll
    for (int j = 0; j < 8; j++){
        int k = kbase + j;
        float wv = which == 0 ? W1[((size_t)(l * 512) + c * 128 + col) * 128 + k]
                              : W2[((size_t)(l * 128) + col) * 512 + c * 128 + k];
        unsigned short hi = f2b(wv);
        unsigned short lo = f2b(wv - b2f(hi));
        dst[ob + j] = hi;
        dst[ob + 512 + j] = lo;
    }
}

// ------- GIN aggregation + bf16x2 split: 32 lanes/node, float4, 4-deep unroll -------
__global__ __launch_bounds__(256) void agg_split_kernel(
    const float* __restrict__ h, const int* __restrict__ row_ptr,
    const int* __restrict__ colv,
    unsigned short* __restrict__ zhi, unsigned short* __restrict__ zlo, int N)
{
    int t = blockIdx.x * 256 + threadIdx.x;
    int i = t >> 5;
    if (i >= N) return;
    int vo = (t & 31);                       // float4 slot 0..31
    const float4* hv = reinterpret_cast<const float4*>(h);
    int p0 = row_ptr[i], p1 = row_ptr[i + 1];
    float4 acc = hv[(size_t)i * 32 + vo];
    int p = p0;
    for (; p + 4 <= p1; p += 4){
        int s0 = colv[p], s1 = colv[p + 1], s2 = colv[p + 2], s3 = colv[p + 3];
        float4 a = hv[(size_t)s0 * 32 + vo];
        float4 b = hv[(size_t)s1 * 32 + vo];
        float4 c = hv[(size_t)s2 * 32 + vo];
        float4 d = hv[(size_t)s3 * 32 + vo];
        acc.x += (a.x + b.x) + (c.x + d.x);
        acc.y += (a.y + b.y) + (c.y + d.y);
        acc.z += (a.z + b.z) + (c.z + d.z);
        acc.w += (a.w + b.w) + (c.w + d.w);
    }
    for (; p < p1; p++){
        float4 a = hv[(size_t)colv[p] * 32 + vo];
        acc.x += a.x; acc.y += a.y; acc.z += a.z; acc.w += a.w;
    }
    float vals[4] = {acc.x, acc.y, acc.z, acc.w};
    unsigned int h01, h23, l01, l23;
    {
        unsigned short hh[4], ll[4];
        #pragma unroll
        for (int j = 0; j < 4; j++){
            hh[j] = f2b(vals[j]);
            ll[j] = f2b(vals[j] - b2f(hh[j]));
        }
        h01 = (unsigned int)hh[0] | ((unsigned int)hh[1] << 16);
        h23 = (unsigned int)hh[2] | ((unsigned int)hh[3] << 16);
        l01 = (unsigned int)ll[0] | ((unsigned int)ll[1] << 16);
        l23 = (unsigned int)ll[2] | ((unsigned int)ll[3] << 16);
    }
    uint2* ph = reinterpret_cast<uint2*>(zhi + (size_t)i * 128 + vo * 4);
    *ph = make_uint2(h01, h23);
    uint2* pl = reinterpret_cast<uint2*>(zlo + (size_t)i * 128 + vo * 4);
    *pl = make_uint2(l01, l23);
}

// -------- GEMM1: z1[:, c0*128 .. (c0+nc)*128) = z0 @ W1^T, BN stats via atomics --------
__global__ __launch_bounds__(256) void gemm1_all_k(
    const unsigned short* __restrict__ Ahi_g, const unsigned short* __restrict__ Alo_g,
    const unsigned short* __restrict__ Bp, float* __restrict__ Z1,
    float* __restrict__ bn_acc, int c0, int nc, int N)
{
    __shared__ __align__(16) unsigned short Ah[128][136];
    __shared__ __align__(16) unsigned short Al[128][136];
    int tid = threadIdx.x, lane = tid & 63, w = tid >> 6;
    int wr = w >> 1, wc = w & 1;
    int r_lo = lane & 15, kg = lane >> 4;
    int m0 = blockIdx.x * 128;
    int ld = nc * 128;

    // stage full 128x128 A tile (hi+lo) once.  uint4 = 8 shorts.
    {
        int r = tid >> 1, hf = tid & 1;
        int grow = m0 + r;
        #pragma unroll
        for (int j = 0; j < 8; j++){
            int kc = hf * 64 + j * 8;
            uint4 hvv = make_uint4(0, 0, 0, 0), lvv = make_uint4(0, 0, 0, 0);
            if (grow < N){
                hvv = *reinterpret_cast<const uint4*>(Ahi_g + (size_t)grow * 128 + kc);
                lvv = *reinterpret_cast<const uint4*>(Alo_g + (size_t)grow * 128 + kc);
            }
            *reinterpret_cast<uint4*>(&Ah[r][kc]) = hvv;
            *reinterpret_cast<uint4*>(&Al[r][kc]) = lvv;
        }
    }
    __syncthreads();

    for (int c = 0; c < nc; c++){
        const bf16x8* Bv = reinterpret_cast<const bf16x8*>(Bp) + (size_t)(c0 + c) * 4096;
        f32x4 acc[4][4];
        #pragma unroll
        for (int i = 0; i < 4; i++)
            #pragma unroll
            for (int j = 0; j < 4; j++) acc[i][j] = (f32x4){0.f, 0.f, 0.f, 0.f};

        for (int kk = 0; kk < 4; kk++){
            bf16x8 bh[4], bl[4];
            #pragma unroll
            for (int nf = 0; nf < 4; nf++){
                int ob = ((kk * 2 + wc) * 4 + nf) * 2;
                bh[nf] = Bv[(ob + 0) * 64 + lane];
                bl[nf] = Bv[(ob + 1) * 64 + lane];
            }
            bf16x8 ah[4], alr[4];
            #pragma unroll
            for (int mf = 0; mf < 4; mf++){
                int ar = wr * 64 + mf * 16 + r_lo;
                ah[mf]  = *reinterpret_cast<const bf16x8*>(&Ah[ar][kk * 32 + kg * 8]);
                alr[mf] = *reinterpret_cast<const bf16x8*>(&Al[ar][kk * 32 + kg * 8]);
            }
            #pragma unroll
            for (int mf = 0; mf < 4; mf++)
                #pragma unroll
                for (int nf = 0; nf < 4; nf++){
                    acc[mf][nf] = __builtin_amdgcn_mfma_f32_16x16x32_bf16(ah[mf],  bh[nf], acc[mf][nf], 0, 0, 0);
                    acc[mf][nf] = __builtin_amdgcn_mfma_f32_16x16x32_bf16(ah[mf],  bl[nf], acc[mf][nf], 0, 0, 0);
                    acc[mf][nf] = __builtin_amdgcn_mfma_f32_16x16x32_bf16(alr[mf], bh[nf], acc[mf][nf], 0, 0, 0);
                }
        }

        // epilogue: write z1 chunk + BN column sums
        #pragma unroll
        for (int nf = 0; nf < 4; nf++){
            int col = wc * 64 + nf * 16 + r_lo;
            float s = 0.f, q = 0.f;
            #pragma unroll
            for (int mf = 0; mf < 4; mf++)
                #pragma unroll
                for (int r = 0; r < 4; r++){
                    int row = m0 + wr * 64 + mf * 16 + kg * 4 + r;
                    if (row < N){
                        float v = acc[mf][nf][r];
                        Z1[(size_t)row * ld + c * 128 + col] = v;
                        s += v; q += v * v;
                    }
                }
            s += __shfl_xor(s, 16); s += __shfl_xor(s, 32);
            q += __shfl_xor(q, 16); q += __shfl_xor(q, 32);
            if (lane < 16){
                atomicAdd(&bn_acc[(c0 + c) * 256 + col], s);
                atomicAdd(&bn_acc[(c0 + c) * 256 + 128 + col], q);
            }
        }
    }
}

// ------- BN finalize -------
__global__ void bn_final_k(const float* __restrict__ bn_acc,
                           const float* __restrict__ bng, const float* __restrict__ bnb,
                           float* __restrict__ sc, float* __restrict__ sh,
                           int l, int c0, float invN){
    int colg = c0 * 128 + threadIdx.x;
    float s = bn_acc[(colg >> 7) * 256 + (colg & 127)];
    float q = bn_acc[(colg >> 7) * 256 + 128 + (colg & 127)];
    float mu = s * invN;
    float var = q * invN - mu * mu;
    float inv = rsqrtf(var + 1e-5f);
    float g = bng[l * 512 + colg] * inv;
    sc[colg] = g;
    sh[colg] = bnb[l * 512 + colg] - mu * g;
}

// ------- GEMM2 (K over this set's cols): z2 (+)= selu(bn(z1)) @ W2^T (+b2) -------
__global__ __launch_bounds__(256) void gemm2_all_k(
    const float* __restrict__ Z1, const unsigned short* __restrict__ Bp,
    float* __restrict__ Z, const float* __restrict__ bsc, const float* __restrict__ bsh,
    const float* __restrict__ b2l, int c0, int nc, int first, int N)
{
    __shared__ __align__(16) unsigned short Ah[128][40];
    __shared__ __align__(16) unsigned short Al[128][40];
    __shared__ float s_sc[512], s_sh[512];
    int tid = threadIdx.x, lane = tid & 63, w = tid >> 6;
    int wr = w >> 1, wc = w & 1;
    int r_lo = lane & 15, kg = lane >> 4;
    int m0 = blockIdx.x * 128;
    int ld = nc * 128;
    int nkk = nc * 4;
    for (int t = tid; t < ld; t += 256){
        s_sc[t] = bsc[c0 * 128 + t];
        s_sh[t] = bsh[c0 * 128 + t];
    }
    f32x4 acc[4][4];
    #pragma unroll
    for (int i = 0; i < 4; i++)
        #pragma unroll
        for (int j = 0; j < 4; j++) acc[i][j] = (f32x4){0.f, 0.f, 0.f, 0.f};

    const bf16x8* Bv = reinterpret_cast<const bf16x8*>(Bp);
    int srow = tid >> 1, sseg = tid & 1;

    for (int kk = 0; kk < nkk; kk++){
        int kkf = c0 * 4 + kk;
        __syncthreads();
        int grow = m0 + srow;
        float vv[16];
        if (grow < N){
            const float4* pc = reinterpret_cast<const float4*>(Z1 + (size_t)grow * ld + kk * 32 + sseg * 16);
            float4 v0 = pc[0], v1 = pc[1], v2 = pc[2], v3 = pc[3];
            vv[0]=v0.x; vv[1]=v0.y; vv[2]=v0.z; vv[3]=v0.w;
            vv[4]=v1.x; vv[5]=v1.y; vv[6]=v1.z; vv[7]=v1.w;
            vv[8]=v2.x; vv[9]=v2.y; vv[10]=v2.z; vv[11]=v2.w;
            vv[12]=v3.x; vv[13]=v3.y; vv[14]=v3.z; vv[15]=v3.w;
        } else {
            #pragma unroll
            for (int i = 0; i < 16; i++) vv[i] = 0.f;
        }
        union { uint4 u4[2]; unsigned short us[16]; } uh, ul;
        #pragma unroll
        for (int i = 0; i < 16; i++){
            int k = kk * 32 + sseg * 16 + i;
            float tt = selu_f(fmaf(vv[i], s_sc[k], s_sh[k]));
            unsigned short hi = f2b(tt);
            uh.us[i] = hi;
            ul.us[i] = f2b(tt - b2f(hi));
        }
        uint4* dh = reinterpret_cast<uint4*>(&Ah[srow][sseg * 16]);
        dh[0] = uh.u4[0]; dh[1] = uh.u4[1];
        uint4* dl = reinterpret_cast<uint4*>(&Al[srow][sseg * 16]);
        dl[0] = ul.u4[0]; dl[1] = ul.u4[1];
        __syncthreads();

        bf16x8 bh[4], bl[4];
        #pragma unroll
        for (int nf = 0; nf < 4; nf++){
            int ob = ((kkf * 2 + wc) * 4 + nf) * 2;
            bh[nf] = Bv[(ob + 0) * 64 + lane];
            bl[nf] = Bv[(ob + 1) * 64 + lane];
        }
        bf16x8 ah[4], alr[4];
        #pragma unroll
        for (int mf = 0; mf < 4; mf++){
            int ar = wr * 64 + mf * 16 + r_lo;
            ah[mf]  = *reinterpret_cast<const bf16x8*>(&Ah[ar][kg * 8]);
            alr[mf] = *reinterpret_cast<const bf16x8*>(&Al[ar][kg * 8]);
        }
        #pragma unroll
        for (int mf = 0; mf < 4; mf++)
            #pragma unroll
            for (int nf = 0; nf < 4; nf++){
                acc[mf][nf] = __builtin_amdgcn_mfma_f32_16x16x32_bf16(ah[mf],  bh[nf], acc[mf][nf], 0, 0, 0);
                acc[mf][nf] = __builtin_amdgcn_mfma_f32_16x16x32_bf16(ah[mf],  bl[nf], acc[mf][nf], 0, 0, 0);
                acc[mf][nf] = __builtin_amdgcn_mfma_f32_16x16x32_bf16(alr[mf], bh[nf], acc[mf][nf], 0, 0, 0);
            }
    }

    #pragma unroll
    for (int nf = 0; nf < 4; nf++){
        int col = wc * 64 + nf * 16 + r_lo;
        #pragma unroll
        for (int mf = 0; mf < 4; mf++)
            #pragma unroll
            for (int r = 0; r < 4; r++){
                int row = m0 + wr * 64 + mf * 16 + kg * 4 + r;
                if (row < N){
                    size_t idx = (size_t)row * 128 + col;
                    float b0 = first ? b2l[col] : Z[idx];
                    Z[idx] = b0 + acc[mf][nf][r];
                }
            }
    }
}

// ---------------- GraphNorm stats (batch sorted) ----------------
__global__ void gn_stats_kernel(const float* __restrict__ z2, const int* __restrict__ batch,
                                float* __restrict__ gsum, float* __restrict__ gsq, int N){
    __shared__ int sb[128];
    int c = threadIdx.x;
    int base = blockIdx.x * 128;
    int end = min(128, N - base);
    if (c < end) sb[c] = batch[base + c];
    __syncthreads();
    float s = 0.f, q = 0.f;
    int run_g = sb[0];
    for (int r = 0; r < end; r++){
        int g = sb[r];
        if (g != run_g){
            atomicAdd(&gsum[run_g * 128 + c], s);
            atomicAdd(&gsq[run_g * 128 + c], q);
            s = 0.f; q = 0.f; run_g = g;
        }
        float v = z2[(size_t)(base + r) * 128 + c];
        s += v; q += v * v;
    }
    atomicAdd(&gsum[run_g * 128 + c], s);
    atomicAdd(&gsq[run_g * 128 + c], q);
}

__global__ void gn_final_kernel(float* __restrict__ gsum, float* __restrict__ gsq,
                                const float* __restrict__ cnt,
                                const float* __restrict__ gng, const float* __restrict__ gnb,
                                const float* __restrict__ gna,
                                float* __restrict__ scale, float* __restrict__ shift, int l){
    int g = blockIdx.x, c = threadIdx.x;
    int idx = g * 128 + c;
    float n = cnt[g];
    float m = gsum[idx] / n;
    float e2 = gsq[idx] / n;
    float a = gna[l * 128 + c];
    float var = e2 - (2.f * a - a * a) * m * m;
    float inv = rsqrtf(var + 1e-5f);
    float sc = gng[l * 128 + c] * inv;
    scale[idx] = sc;
    shift[idx] = gnb[l * 128 + c] - a * m * sc;
    gsum[idx] = 0.f;
    gsq[idx] = 0.f;
}

__global__ void gn_apply_kernel(float* __restrict__ z2h, const int* __restrict__ batch,
                                const float* __restrict__ scale, const float* __restrict__ shift,
                                float* __restrict__ pool, int l, int N){
    __shared__ int sb[128];
    int c = threadIdx.x;
    int base = blockIdx.x * 128;
    int end = min(128, N - base);
    if (c < end) sb[c] = batch[base + c];
    __syncthreads();
    int run_g = sb[0];
    float sc = scale[run_g * 128 + c], sh = shift[run_g * 128 + c];
    float psum = 0.f;
    for (int r = 0; r < end; r++){
        int g = sb[r];
        if (g != run_g){
            atomicAdd(&pool[run_g * 512 + l * 128 + c], psum);
            psum = 0.f; run_g = g;
            sc = scale[g * 128 + c]; sh = shift[g * 128 + c];
        }
        size_t idx = (size_t)(base + r) * 128 + c;
        float v = fmaf(z2h[idx], sc, sh);
        v = selu_f(v);
        z2h[idx] = v;
        psum += v;
    }
    atomicAdd(&pool[run_g * 512 + l * 128 + c], psum);
}

__global__ void final_kernel(const float* __restrict__ pool, const float* __restrict__ cnt,
                             float* __restrict__ out, int n){
    int i = blockIdx.x * 256 + threadIdx.x;
    if (i < n) out[i] = pool[i] / cnt[i >> 9];
}

extern "C" void kernel_launch(void* const* d_in, const int* in_sizes, int n_in,
                              void* d_out, int out_size, void* d_ws, size_t ws_size,
                              hipStream_t stream){
    const float* x    = (const float*)d_in[0];
    const float* W1   = (const float*)d_in[1];
    const float* bng  = (const float*)d_in[2];
    const float* bnb  = (const float*)d_in[3];
    const float* W2   = (const float*)d_in[4];
    const float* b2   = (const float*)d_in[5];
    const float* gng  = (const float*)d_in[6];
    const float* gnb  = (const float*)d_in[7];
    const float* gna  = (const float*)d_in[8];
    const int*   ei   = (const int*)d_in[9];
    const int*   batch= (const int*)d_in[10];
    int N = in_sizes[0] / 128;
    int E = in_sizes[9] / 2;
    float* out = (float*)d_out;
    int RB = (N + 127) / 128;

    char* ws = (char*)d_ws;
    size_t off = 0;
    auto alloc = [&](size_t bytes) -> char* {
        char* p = ws + off;
        off += (bytes + 255) & ~(size_t)255;
        return p;
    };
    unsigned short* z0hi = (unsigned short*)alloc((size_t)N * 128 * 2);
    unsigned short* z0lo = (unsigned short*)alloc((size_t)N * 128 * 2);
    float* z2     = (float*)alloc((size_t)N * 128 * 4);   // doubles as h
    unsigned short* W1p = (unsigned short*)alloc(524288 * 2);
    unsigned short* W2p = (unsigned short*)alloc(524288 * 2);
    int*   row_ptr= (int*)alloc((size_t)(N + 1) * 4);
    int*   colv   = (int*)alloc((size_t)E * 4);
    int*   counts = (int*)alloc((size_t)N * 4);
    int*   fill   = (int*)alloc((size_t)N * 4);
    float* cnt_f  = (float*)alloc(256 * 4);
    float* bn_acc = (float*)alloc(16 * 256 * 4);   // [l*4+c][sum 128 | sq 128]
    float* bn_sc  = (float*)alloc(512 * 4);
    float* bn_sh  = (float*)alloc(512 * 4);
    float* gn_sum = (float*)alloc(256 * 128 * 4);  // contiguous with gn_sq
    float* gn_sq  = (float*)alloc(256 * 128 * 4);
    float* gn_sc  = (float*)alloc(256 * 128 * 4);
    float* gn_sh  = (float*)alloc(256 * 128 * 4);
    float* pool   = (float*)alloc(256 * 512 * 4);
    // z1 takes the remainder: pick widest chunk set {512,256,128} cols that fits
    size_t remain = ws_size > off ? ws_size - off : 0;
    int nc = 4;
    while (nc > 1 && remain < (size_t)N * (128 * nc) * 4 + 256) nc >>= 1;
    int SETS = 4 / nc;
    float* z1 = (float*)alloc((size_t)N * (128 * nc) * 4);

    hipMemsetAsync(counts, 0, (size_t)N * 4, stream);
    hipMemsetAsync(fill,   0, (size_t)N * 4, stream);
    hipMemsetAsync(bn_acc, 0, 16 * 256 * 4, stream);
    hipMemsetAsync(gn_sum, 0, 2 * 256 * 128 * 4, stream);      // gn_sum + gn_sq
    hipMemsetAsync(pool,   0, 256 * 512 * 4, stream);

    pack_kernel<<<256, 256, 0, stream>>>(W1, W2, W1p, W2p);
    count_kernel<<<(E + 255) / 256, 256, 0, stream>>>(ei + E, counts, E);
    scan_kernel<<<1, 1024, 0, stream>>>(counts, row_ptr, N);
    fill_kernel<<<(E + 255) / 256, 256, 0, stream>>>(ei, row_ptr, fill, colv, E);
    cnt_bs_kernel<<<1, 256, 0, stream>>>(batch, cnt_f, N);

    const float* hcur = x;
    float invN = 1.f / (float)N;
    for (int l = 0; l < 4; l++){
        agg_split_kernel<<<(N + 7) / 8, 256, 0, stream>>>(hcur, row_ptr, colv, z0hi, z0lo, N);
        for (int s = 0; s < SETS; s++){
            int c0 = s * nc;
            gemm1_all_k<<<RB, 256, 0, stream>>>(z0hi, z0lo, W1p + (size_t)l * 131072,
                                                z1, bn_acc + l * 1024, c0, nc, N);
            bn_final_k<<<1, nc * 128, 0, stream>>>(bn_acc + l * 1024, bng, bnb,
                                                   bn_sc, bn_sh, l, c0, invN);
            gemm2_all_k<<<RB, 256, 0, stream>>>(z1, W2p + (size_t)l * 131072, z2,
                                                bn_sc, bn_sh, b2 + l * 128,
                                                c0, nc, (s == 0) ? 1 : 0, N);
        }
        gn_stats_kernel<<<RB, 128, 0, stream>>>(z2, batch, gn_sum, gn_sq, N);
        gn_final_kernel<<<256, 128, 0, stream>>>(gn_sum, gn_sq, cnt_f, gng, gnb, gna,
                                                 gn_sc, gn_sh, l);
        gn_apply_kernel<<<RB, 128, 0, stream>>>(z2, batch, gn_sc, gn_sh, pool, l, N);
        hcur = z2;
    }
    final_kernel<<<(out_size + 255) / 256, 256, 0, stream>>>(pool, cnt_f, out, out_size);
}

// Round 6
// 1790.262 us; speedup vs baseline: 2.8055x; 1.0845x over previous
//
#include <hip/hip_runtime.h>
#include <hip/hip_bf16.h>

// GIN 4-layer forward, round 6: kill the z1 round-trip.
// stats_k = gemm1 MFMA, no stores, BN atomics only.
// fused_k = recompute z1 chunk in regs -> BN+SELU+split -> LDS -> gemm2 MFMA -> z2 once.

typedef __attribute__((ext_vector_type(8))) short bf16x8;
typedef __attribute__((ext_vector_type(4))) float f32x4;

__device__ __forceinline__ unsigned short f2b(float x){
    __hip_bfloat16 h = __float2bfloat16(x);
    return *reinterpret_cast<unsigned short*>(&h);
}
__device__ __forceinline__ float b2f(unsigned short u){
    __hip_bfloat16 h;
    *reinterpret_cast<unsigned short*>(&h) = u;
    return __bfloat162float(h);
}
__device__ __forceinline__ float selu_f(float x){
    const float sc = 1.0507009873554805f, al = 1.6732632423543772f;
    return x > 0.f ? sc * x : sc * al * (__expf(x) - 1.f);
}

// ---------------- CSR build ----------------
__global__ void count_kernel(const int* __restrict__ dst, int* __restrict__ counts, int E){
    int e = blockIdx.x * 256 + threadIdx.x;
    if (e < E) atomicAdd(&counts[dst[e]], 1);
}

__global__ void cnt_bs_kernel(const int* __restrict__ batch, float* __restrict__ cnt, int N){
    __shared__ int sb[257];
    int g = threadIdx.x;
    int lo = 0, hi = N;
    while (lo < hi){ int mid = (lo + hi) >> 1; if (batch[mid] < g) lo = mid + 1; else hi = mid; }
    sb[g] = lo;
    if (g == 0) sb[256] = N;
    __syncthreads();
    cnt[g] = fmaxf((float)(sb[g + 1] - sb[g]), 1.f);
}

__global__ __launch_bounds__(1024) void scan_kernel(const int* __restrict__ counts,
                                                    int* __restrict__ row_ptr, int N){
    __shared__ int wsum[16];
    __shared__ int wpre[16];
    __shared__ int s_total;
    __shared__ int s_running;
    int tid = threadIdx.x;
    int lane = tid & 63, wid = tid >> 6;
    if (tid == 0) s_running = 0;
    __syncthreads();
    for (int base = 0; base < N; base += 4096){
        int idx0 = base + tid * 4;
        int v[4];
        #pragma unroll
        for (int j = 0; j < 4; j++) v[j] = (idx0 + j < N) ? counts[idx0 + j] : 0;
        int tsum = v[0] + v[1] + v[2] + v[3];
        int x = tsum;
        #pragma unroll
        for (int off = 1; off < 64; off <<= 1){
            int y = __shfl_up(x, off, 64);
            if (lane >= off) x += y;
        }
        if (lane == 63) wsum[wid] = x;
        __syncthreads();
        if (wid == 0 && lane < 16){
            int w = wsum[lane];
            int xx = w;
            #pragma unroll
            for (int off = 1; off < 16; off <<= 1){
                int y = __shfl_up(xx, off, 64);
                if (lane >= off) xx += y;
            }
            wpre[lane] = xx - w;
            if (lane == 15) s_total = xx;
        }
        __syncthreads();
        int run = s_running + wpre[wid] + (x - tsum);
        #pragma unroll
        for (int j = 0; j < 4; j++){
            if (idx0 + j < N) row_ptr[idx0 + j] = run;
            run += v[j];
        }
        __syncthreads();
        if (tid == 0) s_running += s_total;
        __syncthreads();
    }
    if (tid == 0) row_ptr[N] = s_running;
}

__global__ void fill_kernel(const int* __restrict__ ei, const int* __restrict__ row_ptr,
                            int* __restrict__ fill, int* __restrict__ colv, int E){
    int e = blockIdx.x * 256 + threadIdx.x;
    if (e < E){
        int s = ei[e];
        int d = ei[E + e];
        int pos = atomicAdd(&fill[d], 1);
        colv[row_ptr[d] + pos] = s;
    }
}

// ------------- weight pre-pack: f32 -> bf16 hi/lo fragments -------------
__global__ void pack_kernel(const float* __restrict__ W1, const float* __restrict__ W2,
                            unsigned short* __restrict__ W1p, unsigned short* __restrict__ W2p){
    int t = blockIdx.x * 256 + threadIdx.x;   // 65536 total
    int which = t >> 15;
    int u = t & 32767;
    int lane = u & 63; u >>= 6;
    int nf = u & 3; u >>= 2;
    int wc = u & 1; u >>= 1;
    int kk = u & 3; u >>= 2;
    int c = u & 3; u >>= 2;
    int l = u;
    int col = wc * 64 + nf * 16 + (lane & 15);
    int kbase = kk * 32 + (lane >> 4) * 8;
    size_t ob = ((((((size_t)(l * 4 + c) * 4 + kk) * 2 + wc) * 4 + nf) * 2) * 512) + lane * 8;
    unsigned short* dst = which == 0 ? W1p : W2p;
    #pragma unroll
    for (int j = 0; j < 8; j++){
        int k = kbase + j;
        float wv = which == 0 ? W1[((size_t)(l * 512) + c * 128 + col) * 128 + k]
                              : W2[((size_t)(l * 128) + col) * 512 + c * 128 + k];
        unsigned short hi = f2b(wv);
        unsigned short lo = f2b(wv - b2f(hi));
        dst[ob + j] = hi;
        dst[ob + 512 + j] = lo;
    }
}

// ------- GIN aggregation + bf16x2 split: 32 lanes/node, float4, 4-deep unroll -------
__global__ __launch_bounds__(256) void agg_split_kernel(
    const float* __restrict__ h, const int* __restrict__ row_ptr,
    const int* __restrict__ colv,
    unsigned short* __restrict__ zhi, unsigned short* __restrict__ zlo, int N)
{
    int t = blockIdx.x * 256 + threadIdx.x;
    int i = t >> 5;
    if (i >= N) return;
    int vo = (t & 31);
    const float4* hv = reinterpret_cast<const float4*>(h);
    int p0 = row_ptr[i], p1 = row_ptr[i + 1];
    float4 acc = hv[(size_t)i * 32 + vo];
    int p = p0;
    for (; p + 4 <= p1; p += 4){
        int s0 = colv[p], s1 = colv[p + 1], s2 = colv[p + 2], s3 = colv[p + 3];
        float4 a = hv[(size_t)s0 * 32 + vo];
        float4 b = hv[(size_t)s1 * 32 + vo];
        float4 c = hv[(size_t)s2 * 32 + vo];
        float4 d = hv[(size_t)s3 * 32 + vo];
        acc.x += (a.x + b.x) + (c.x + d.x);
        acc.y += (a.y + b.y) + (c.y + d.y);
        acc.z += (a.z + b.z) + (c.z + d.z);
        acc.w += (a.w + b.w) + (c.w + d.w);
    }
    for (; p < p1; p++){
        float4 a = hv[(size_t)colv[p] * 32 + vo];
        acc.x += a.x; acc.y += a.y; acc.z += a.z; acc.w += a.w;
    }
    float vals[4] = {acc.x, acc.y, acc.z, acc.w};
    unsigned int h01, h23, l01, l23;
    {
        unsigned short hh[4], ll[4];
        #pragma unroll
        for (int j = 0; j < 4; j++){
            hh[j] = f2b(vals[j]);
            ll[j] = f2b(vals[j] - b2f(hh[j]));
        }
        h01 = (unsigned int)hh[0] | ((unsigned int)hh[1] << 16);
        h23 = (unsigned int)hh[2] | ((unsigned int)hh[3] << 16);
        l01 = (unsigned int)ll[0] | ((unsigned int)ll[1] << 16);
        l23 = (unsigned int)ll[2] | ((unsigned int)ll[3] << 16);
    }
    uint2* ph = reinterpret_cast<uint2*>(zhi + (size_t)i * 128 + vo * 4);
    *ph = make_uint2(h01, h23);
    uint2* pl = reinterpret_cast<uint2*>(zlo + (size_t)i * 128 + vo * 4);
    *pl = make_uint2(l01, l23);
}

// -------- stats pass: gemm1 MFMA, NO stores, BN sum/sq atomics only --------
__global__ __launch_bounds__(256) void stats_k(
    const unsigned short* __restrict__ Ahi_g, const unsigned short* __restrict__ Alo_g,
    const unsigned short* __restrict__ Bp, float* __restrict__ bn_acc, int N)
{
    __shared__ __align__(16) unsigned short Ah[128][136];
    __shared__ __align__(16) unsigned short Al[128][136];
    int tid = threadIdx.x, lane = tid & 63, w = tid >> 6;
    int wr = w >> 1, wc = w & 1;
    int r_lo = lane & 15, kg = lane >> 4;
    int m0 = blockIdx.x * 128;

    {
        int r = tid >> 1, hf = tid & 1;
        int grow = m0 + r;
        #pragma unroll
        for (int j = 0; j < 8; j++){
            int kc = hf * 64 + j * 8;
            uint4 hvv = make_uint4(0, 0, 0, 0), lvv = make_uint4(0, 0, 0, 0);
            if (grow < N){
                hvv = *reinterpret_cast<const uint4*>(Ahi_g + (size_t)grow * 128 + kc);
                lvv = *reinterpret_cast<const uint4*>(Alo_g + (size_t)grow * 128 + kc);
            }
            *reinterpret_cast<uint4*>(&Ah[r][kc]) = hvv;
            *reinterpret_cast<uint4*>(&Al[r][kc]) = lvv;
        }
    }
    __syncthreads();

    for (int c = 0; c < 4; c++){
        const bf16x8* Bv = reinterpret_cast<const bf16x8*>(Bp) + (size_t)c * 4096;
        f32x4 acc[4][4];
        #pragma unroll
        for (int i = 0; i < 4; i++)
            #pragma unroll
            for (int j = 0; j < 4; j++) acc[i][j] = (f32x4){0.f, 0.f, 0.f, 0.f};

        for (int kk = 0; kk < 4; kk++){
            bf16x8 bh[4], bl[4];
            #pragma unroll
            for (int nf = 0; nf < 4; nf++){
                int ob = ((kk * 2 + wc) * 4 + nf) * 2;
                bh[nf] = Bv[(ob + 0) * 64 + lane];
                bl[nf] = Bv[(ob + 1) * 64 + lane];
            }
            bf16x8 ah[4], alr[4];
            #pragma unroll
            for (int mf = 0; mf < 4; mf++){
                int ar = wr * 64 + mf * 16 + r_lo;
                ah[mf]  = *reinterpret_cast<const bf16x8*>(&Ah[ar][kk * 32 + kg * 8]);
                alr[mf] = *reinterpret_cast<const bf16x8*>(&Al[ar][kk * 32 + kg * 8]);
            }
            #pragma unroll
            for (int mf = 0; mf < 4; mf++)
                #pragma unroll
                for (int nf = 0; nf < 4; nf++){
                    acc[mf][nf] = __builtin_amdgcn_mfma_f32_16x16x32_bf16(ah[mf],  bh[nf], acc[mf][nf], 0, 0, 0);
                    acc[mf][nf] = __builtin_amdgcn_mfma_f32_16x16x32_bf16(ah[mf],  bl[nf], acc[mf][nf], 0, 0, 0);
                    acc[mf][nf] = __builtin_amdgcn_mfma_f32_16x16x32_bf16(alr[mf], bh[nf], acc[mf][nf], 0, 0, 0);
                }
        }

        #pragma unroll
        for (int nf = 0; nf < 4; nf++){
            int col = wc * 64 + nf * 16 + r_lo;
            float s = 0.f, q = 0.f;
            #pragma unroll
            for (int mf = 0; mf < 4; mf++)
                #pragma unroll
                for (int r = 0; r < 4; r++){
                    int row = m0 + wr * 64 + mf * 16 + kg * 4 + r;
                    if (row < N){
                        float v = acc[mf][nf][r];
                        s += v; q += v * v;
                    }
                }
            s += __shfl_xor(s, 16); s += __shfl_xor(s, 32);
            q += __shfl_xor(q, 16); q += __shfl_xor(q, 32);
            if (lane < 16){
                atomicAdd(&bn_acc[c * 256 + col], s);
                atomicAdd(&bn_acc[c * 256 + 128 + col], q);
            }
        }
    }
}

// ------- BN finalize: all 512 cols -------
__global__ void bn_final_k(const float* __restrict__ bn_acc,
                           const float* __restrict__ bng, const float* __restrict__ bnb,
                           float* __restrict__ sc, float* __restrict__ sh,
                           int l, float invN){
    int colg = threadIdx.x;   // 512 threads
    float s = bn_acc[(colg >> 7) * 256 + (colg & 127)];
    float q = bn_acc[(colg >> 7) * 256 + 128 + (colg & 127)];
    float mu = s * invN;
    float var = q * invN - mu * mu;
    float inv = rsqrtf(var + 1e-5f);
    float g = bng[l * 512 + colg] * inv;
    sc[colg] = g;
    sh[colg] = bnb[l * 512 + colg] - mu * g;
}

// ------- fused: recompute z1 chunk -> BN+SELU+split -> LDS -> gemm2 -> z2 once -------
__global__ __launch_bounds__(256, 1) void fused_k(
    const unsigned short* __restrict__ Ahi_g, const unsigned short* __restrict__ Alo_g,
    const unsigned short* __restrict__ B1p, const unsigned short* __restrict__ B2p,
    float* __restrict__ Z, const float* __restrict__ bsc, const float* __restrict__ bsh,
    const float* __restrict__ b2l, int N)
{
    __shared__ __align__(16) unsigned short Ah[128][136];
    __shared__ __align__(16) unsigned short Al[128][136];
    __shared__ __align__(16) unsigned short Ph[128][136];
    __shared__ __align__(16) unsigned short Pl[128][136];
    __shared__ float s_sc[512], s_sh[512];
    int tid = threadIdx.x, lane = tid & 63, w = tid >> 6;
    int wr = w >> 1, wc = w & 1;
    int r_lo = lane & 15, kg = lane >> 4;
    int m0 = blockIdx.x * 128;

    for (int t = tid; t < 512; t += 256){ s_sc[t] = bsc[t]; s_sh[t] = bsh[t]; }
    {
        int r = tid >> 1, hf = tid & 1;
        int grow = m0 + r;
        #pragma unroll
        for (int j = 0; j < 8; j++){
            int kc = hf * 64 + j * 8;
            uint4 hvv = make_uint4(0, 0, 0, 0), lvv = make_uint4(0, 0, 0, 0);
            if (grow < N){
                hvv = *reinterpret_cast<const uint4*>(Ahi_g + (size_t)grow * 128 + kc);
                lvv = *reinterpret_cast<const uint4*>(Alo_g + (size_t)grow * 128 + kc);
            }
            *reinterpret_cast<uint4*>(&Ah[r][kc]) = hvv;
            *reinterpret_cast<uint4*>(&Al[r][kc]) = lvv;
        }
    }
    __syncthreads();

    f32x4 acc2[4][4];
    #pragma unroll
    for (int i = 0; i < 4; i++)
        #pragma unroll
        for (int j = 0; j < 4; j++) acc2[i][j] = (f32x4){0.f, 0.f, 0.f, 0.f};

    for (int c = 0; c < 4; c++){
        // ---- gemm1 chunk: z1_c in registers ----
        f32x4 acc1[4][4];
        #pragma unroll
        for (int i = 0; i < 4; i++)
            #pragma unroll
            for (int j = 0; j < 4; j++) acc1[i][j] = (f32x4){0.f, 0.f, 0.f, 0.f};

        const bf16x8* B1v = reinterpret_cast<const bf16x8*>(B1p) + (size_t)c * 4096;
        for (int kk = 0; kk < 4; kk++){
            bf16x8 bh[4], bl[4];
            #pragma unroll
            for (int nf = 0; nf < 4; nf++){
                int ob = ((kk * 2 + wc) * 4 + nf) * 2;
                bh[nf] = B1v[(ob + 0) * 64 + lane];
                bl[nf] = B1v[(ob + 1) * 64 + lane];
            }
            bf16x8 ah[4], alr[4];
            #pragma unroll
            for (int mf = 0; mf < 4; mf++){
                int ar = wr * 64 + mf * 16 + r_lo;
                ah[mf]  = *reinterpret_cast<const bf16x8*>(&Ah[ar][kk * 32 + kg * 8]);
                alr[mf] = *reinterpret_cast<const bf16x8*>(&Al[ar][kk * 32 + kg * 8]);
            }
            #pragma unroll
            for (int mf = 0; mf < 4; mf++)
                #pragma unroll
                for (int nf = 0; nf < 4; nf++){
                    acc1[mf][nf] = __builtin_amdgcn_mfma_f32_16x16x32_bf16(ah[mf],  bh[nf], acc1[mf][nf], 0, 0, 0);
                    acc1[mf][nf] = __builtin_amdgcn_mfma_f32_16x16x32_bf16(ah[mf],  bl[nf], acc1[mf][nf], 0, 0, 0);
                    acc1[mf][nf] = __builtin_amdgcn_mfma_f32_16x16x32_bf16(alr[mf], bh[nf], acc1[mf][nf], 0, 0, 0);
                }
        }

        // ---- BN + SELU + split -> Ph/Pl (protect prev gemm2 reads first) ----
        __syncthreads();
        #pragma unroll
        for (int nf = 0; nf < 4; nf++){
            int colk = wc * 64 + nf * 16 + r_lo;
            float scv = s_sc[c * 128 + colk], shv = s_sh[c * 128 + colk];
            #pragma unroll
            for (int mf = 0; mf < 4; mf++)
                #pragma unroll
                for (int r = 0; r < 4; r++){
                    int rl = wr * 64 + mf * 16 + kg * 4 + r;
                    float t = selu_f(fmaf(acc1[mf][nf][r], scv, shv));
                    unsigned short hi = f2b(t);
                    Ph[rl][colk] = hi;
                    Pl[rl][colk] = f2b(t - b2f(hi));
                }
        }
        __syncthreads();

        // ---- gemm2 accumulate over this K slice ----
        for (int kk2 = 0; kk2 < 4; kk2++){
            int kkf = c * 4 + kk2;
            const bf16x8* B2v = reinterpret_cast<const bf16x8*>(B2p);
            bf16x8 bh[4], bl[4];
            #pragma unroll
            for (int nf = 0; nf < 4; nf++){
                int ob = ((kkf * 2 + wc) * 4 + nf) * 2;
                bh[nf] = B2v[(ob + 0) * 64 + lane];
                bl[nf] = B2v[(ob + 1) * 64 + lane];
            }
            bf16x8 ah[4], alr[4];
            #pragma unroll
            for (int mf = 0; mf < 4; mf++){
                int ar = wr * 64 + mf * 16 + r_lo;
                ah[mf]  = *reinterpret_cast<const bf16x8*>(&Ph[ar][kk2 * 32 + kg * 8]);
                alr[mf] = *reinterpret_cast<const bf16x8*>(&Pl[ar][kk2 * 32 + kg * 8]);
            }
            #pragma unroll
            for (int mf = 0; mf < 4; mf++)
                #pragma unroll
                for (int nf = 0; nf < 4; nf++){
                    acc2[mf][nf] = __builtin_amdgcn_mfma_f32_16x16x32_bf16(ah[mf],  bh[nf], acc2[mf][nf], 0, 0, 0);
                    acc2[mf][nf] = __builtin_amdgcn_mfma_f32_16x16x32_bf16(ah[mf],  bl[nf], acc2[mf][nf], 0, 0, 0);
                    acc2[mf][nf] = __builtin_amdgcn_mfma_f32_16x16x32_bf16(alr[mf], bh[nf], acc2[mf][nf], 0, 0, 0);
                }
        }
    }

    // ---- write z2 = acc2 + b2 ----
    #pragma unroll
    for (int nf = 0; nf < 4; nf++){
        int col = wc * 64 + nf * 16 + r_lo;
        float bv = b2l[col];
        #pragma unroll
        for (int mf = 0; mf < 4; mf++)
            #pragma unroll
            for (int r = 0; r < 4; r++){
                int row = m0 + wr * 64 + mf * 16 + kg * 4 + r;
                if (row < N)
                    Z[(size_t)row * 128 + col] = bv + acc2[mf][nf][r];
            }
    }
}

// ---------------- GraphNorm stats (batch sorted) ----------------
__global__ void gn_stats_kernel(const float* __restrict__ z2, const int* __restrict__ batch,
                                float* __restrict__ gsum, float* __restrict__ gsq, int N){
    __shared__ int sb[128];
    int c = threadIdx.x;
    int base = blockIdx.x * 128;
    int end = min(128, N - base);
    if (c < end) sb[c] = batch[base + c];
    __syncthreads();
    float s = 0.f, q = 0.f;
    int run_g = sb[0];
    for (int r = 0; r < end; r++){
        int g = sb[r];
        if (g != run_g){
            atomicAdd(&gsum[run_g * 128 + c], s);
            atomicAdd(&gsq[run_g * 128 + c], q);
            s = 0.f; q = 0.f; run_g = g;
        }
        float v = z2[(size_t)(base + r) * 128 + c];
        s += v; q += v * v;
    }
    atomicAdd(&gsum[run_g * 128 + c], s);
    atomicAdd(&gsq[run_g * 128 + c], q);
}

__global__ void gn_final_kernel(float* __restrict__ gsum, float* __restrict__ gsq,
                                const float* __restrict__ cnt,
                                const float* __restrict__ gng, const float* __restrict__ gnb,
                                const float* __restrict__ gna,
                                float* __restrict__ scale, float* __restrict__ shift, int l){
    int g = blockIdx.x, c = threadIdx.x;
    int idx = g * 128 + c;
    float n = cnt[g];
    float m = gsum[idx] / n;
    float e2 = gsq[idx] / n;
    float a = gna[l * 128 + c];
    float var = e2 - (2.f * a - a * a) * m * m;
    float inv = rsqrtf(var + 1e-5f);
    float sc = gng[l * 128 + c] * inv;
    scale[idx] = sc;
    shift[idx] = gnb[l * 128 + c] - a * m * sc;
    gsum[idx] = 0.f;
    gsq[idx] = 0.f;
}

__global__ void gn_apply_kernel(float* __restrict__ z2h, const int* __restrict__ batch,
                                const float* __restrict__ scale, const float* __restrict__ shift,
                                float* __restrict__ pool, int l, int N){
    __shared__ int sb[128];
    int c = threadIdx.x;
    int base = blockIdx.x * 128;
    int end = min(128, N - base);
    if (c < end) sb[c] = batch[base + c];
    __syncthreads();
    int run_g = sb[0];
    float sc = scale[run_g * 128 + c], sh = shift[run_g * 128 + c];
    float psum = 0.f;
    for (int r = 0; r < end; r++){
        int g = sb[r];
        if (g != run_g){
            atomicAdd(&pool[run_g * 512 + l * 128 + c], psum);
            psum = 0.f; run_g = g;
            sc = scale[g * 128 + c]; sh = shift[g * 128 + c];
        }
        size_t idx = (size_t)(base + r) * 128 + c;
        float v = fmaf(z2h[idx], sc, sh);
        v = selu_f(v);
        z2h[idx] = v;
        psum += v;
    }
    atomicAdd(&pool[run_g * 512 + l * 128 + c], psum);
}

__global__ void final_kernel(const float* __restrict__ pool, const float* __restrict__ cnt,
                             float* __restrict__ out, int n){
    int i = blockIdx.x * 256 + threadIdx.x;
    if (i < n) out[i] = pool[i] / cnt[i >> 9];
}

extern "C" void kernel_launch(void* const* d_in, const int* in_sizes, int n_in,
                              void* d_out, int out_size, void* d_ws, size_t ws_size,
                              hipStream_t stream){
    const float* x    = (const float*)d_in[0];
    const float* W1   = (const float*)d_in[1];
    const float* bng  = (const float*)d_in[2];
    const float* bnb  = (const float*)d_in[3];
    const float* W2   = (const float*)d_in[4];
    const float* b2   = (const float*)d_in[5];
    const float* gng  = (const float*)d_in[6];
    const float* gnb  = (const float*)d_in[7];
    const float* gna  = (const float*)d_in[8];
    const int*   ei   = (const int*)d_in[9];
    const int*   batch= (const int*)d_in[10];
    int N = in_sizes[0] / 128;
    int E = in_sizes[9] / 2;
    float* out = (float*)d_out;
    int RB = (N + 127) / 128;

    char* ws = (char*)d_ws;
    size_t off = 0;
    auto alloc = [&](size_t bytes) -> char* {
        char* p = ws + off;
        off += (bytes + 255) & ~(size_t)255;
        return p;
    };
    unsigned short* z0hi = (unsigned short*)alloc((size_t)N * 128 * 2);
    unsigned short* z0lo = (unsigned short*)alloc((size_t)N * 128 * 2);
    float* z2     = (float*)alloc((size_t)N * 128 * 4);   // doubles as h
    unsigned short* W1p = (unsigned short*)alloc(524288 * 2);
    unsigned short* W2p = (unsigned short*)alloc(524288 * 2);
    int*   row_ptr= (int*)alloc((size_t)(N + 1) * 4);
    int*   colv   = (int*)alloc((size_t)E * 4);
    int*   counts = (int*)alloc((size_t)N * 4);
    int*   fill   = (int*)alloc((size_t)N * 4);
    float* cnt_f  = (float*)alloc(256 * 4);
    float* bn_acc = (float*)alloc(16 * 256 * 4);   // [l*4+c][sum 128 | sq 128]
    float* bn_sc  = (float*)alloc(512 * 4);
    float* bn_sh  = (float*)alloc(512 * 4);
    float* gn_sum = (float*)alloc(256 * 128 * 4);  // contiguous with gn_sq
    float* gn_sq  = (float*)alloc(256 * 128 * 4);
    float* gn_sc  = (float*)alloc(256 * 128 * 4);
    float* gn_sh  = (float*)alloc(256 * 128 * 4);
    float* pool   = (float*)alloc(256 * 512 * 4);
    (void)ws_size;

    hipMemsetAsync(counts, 0, (size_t)N * 4, stream);
    hipMemsetAsync(fill,   0, (size_t)N * 4, stream);
    hipMemsetAsync(bn_acc, 0, 16 * 256 * 4, stream);
    hipMemsetAsync(gn_sum, 0, 2 * 256 * 128 * 4, stream);      // gn_sum + gn_sq
    hipMemsetAsync(pool,   0, 256 * 512 * 4, stream);

    pack_kernel<<<256, 256, 0, stream>>>(W1, W2, W1p, W2p);
    count_kernel<<<(E + 255) / 256, 256, 0, stream>>>(ei + E, counts, E);
    scan_kernel<<<1, 1024, 0, stream>>>(counts, row_ptr, N);
    fill_kernel<<<(E + 255) / 256, 256, 0, stream>>>(ei, row_ptr, fill, colv, E);
    cnt_bs_kernel<<<1, 256, 0, stream>>>(batch, cnt_f, N);

    const float* hcur = x;
    float invN = 1.f / (float)N;
    for (int l = 0; l < 4; l++){
        agg_split_kernel<<<(N + 7) / 8, 256, 0, stream>>>(hcur, row_ptr, colv, z0hi, z0lo, N);
        stats_k<<<RB, 256, 0, stream>>>(z0hi, z0lo, W1p + (size_t)l * 131072,
                                        bn_acc + l * 1024, N);
        bn_final_k<<<1, 512, 0, stream>>>(bn_acc + l * 1024, bng, bnb,
                                          bn_sc, bn_sh, l, invN);
        fused_k<<<RB, 256, 0, stream>>>(z0hi, z0lo, W1p + (size_t)l * 131072,
                                        W2p + (size_t)l * 131072, z2,
                                        bn_sc, bn_sh, b2 + l * 128, N);
        gn_stats_kernel<<<RB, 128, 0, stream>>>(z2, batch, gn_sum, gn_sq, N);
        gn_final_kernel<<<256, 128, 0, stream>>>(gn_sum, gn_sq, cnt_f, gng, gnb, gna,
                                                 gn_sc, gn_sh, l);
        gn_apply_kernel<<<RB, 128, 0, stream>>>(z2, batch, gn_sc, gn_sh, pool, l, N);
        hcur = z2;
    }
    final_kernel<<<(out_size + 255) / 256, 256, 0, stream>>>(pool, cnt_f, out, out_size);
}

// Round 7
// 1445.318 us; speedup vs baseline: 3.4751x; 1.2387x over previous
//
#include <hip/hip_runtime.h>
#include <hip/hip_bf16.h>

// GIN 4-layer forward, round 7: 8-wave (512-thr) fused_k/stats_k for 2 waves/SIMD
// (r6 was 1 wave/SIMD -> latency-bound), float4-slab GraphNorm kernels.

typedef __attribute__((ext_vector_type(8))) short bf16x8;
typedef __attribute__((ext_vector_type(4))) float f32x4;

__device__ __forceinline__ unsigned short f2b(float x){
    __hip_bfloat16 h = __float2bfloat16(x);
    return *reinterpret_cast<unsigned short*>(&h);
}
__device__ __forceinline__ float b2f(unsigned short u){
    __hip_bfloat16 h;
    *reinterpret_cast<unsigned short*>(&h) = u;
    return __bfloat162float(h);
}
__device__ __forceinline__ float selu_f(float x){
    const float sc = 1.0507009873554805f, al = 1.6732632423543772f;
    return x > 0.f ? sc * x : sc * al * (__expf(x) - 1.f);
}

// ---------------- CSR build ----------------
__global__ void count_kernel(const int* __restrict__ dst, int* __restrict__ counts, int E){
    int e = blockIdx.x * 256 + threadIdx.x;
    if (e < E) atomicAdd(&counts[dst[e]], 1);
}

__global__ void cnt_bs_kernel(const int* __restrict__ batch, float* __restrict__ cnt, int N){
    __shared__ int sb[257];
    int g = threadIdx.x;
    int lo = 0, hi = N;
    while (lo < hi){ int mid = (lo + hi) >> 1; if (batch[mid] < g) lo = mid + 1; else hi = mid; }
    sb[g] = lo;
    if (g == 0) sb[256] = N;
    __syncthreads();
    cnt[g] = fmaxf((float)(sb[g + 1] - sb[g]), 1.f);
}

__global__ __launch_bounds__(1024) void scan_kernel(const int* __restrict__ counts,
                                                    int* __restrict__ row_ptr, int N){
    __shared__ int wsum[16];
    __shared__ int wpre[16];
    __shared__ int s_total;
    __shared__ int s_running;
    int tid = threadIdx.x;
    int lane = tid & 63, wid = tid >> 6;
    if (tid == 0) s_running = 0;
    __syncthreads();
    for (int base = 0; base < N; base += 4096){
        int idx0 = base + tid * 4;
        int v[4];
        #pragma unroll
        for (int j = 0; j < 4; j++) v[j] = (idx0 + j < N) ? counts[idx0 + j] : 0;
        int tsum = v[0] + v[1] + v[2] + v[3];
        int x = tsum;
        #pragma unroll
        for (int off = 1; off < 64; off <<= 1){
            int y = __shfl_up(x, off, 64);
            if (lane >= off) x += y;
        }
        if (lane == 63) wsum[wid] = x;
        __syncthreads();
        if (wid == 0 && lane < 16){
            int w = wsum[lane];
            int xx = w;
            #pragma unroll
            for (int off = 1; off < 16; off <<= 1){
                int y = __shfl_up(xx, off, 64);
                if (lane >= off) xx += y;
            }
            wpre[lane] = xx - w;
            if (lane == 15) s_total = xx;
        }
        __syncthreads();
        int run = s_running + wpre[wid] + (x - tsum);
        #pragma unroll
        for (int j = 0; j < 4; j++){
            if (idx0 + j < N) row_ptr[idx0 + j] = run;
            run += v[j];
        }
        __syncthreads();
        if (tid == 0) s_running += s_total;
        __syncthreads();
    }
    if (tid == 0) row_ptr[N] = s_running;
}

__global__ void fill_kernel(const int* __restrict__ ei, const int* __restrict__ row_ptr,
                            int* __restrict__ fill, int* __restrict__ colv, int E){
    int e = blockIdx.x * 256 + threadIdx.x;
    if (e < E){
        int s = ei[e];
        int d = ei[E + e];
        int pos = atomicAdd(&fill[d], 1);
        colv[row_ptr[d] + pos] = s;
    }
}

// ------------- weight pre-pack: f32 -> bf16 hi/lo fragments -------------
__global__ void pack_kernel(const float* __restrict__ W1, const float* __restrict__ W2,
                            unsigned short* __restrict__ W1p, unsigned short* __restrict__ W2p){
    int t = blockIdx.x * 256 + threadIdx.x;   // 65536 total
    int which = t >> 15;
    int u = t & 32767;
    int lane = u & 63; u >>= 6;
    int nf = u & 3; u >>= 2;
    int wc = u & 1; u >>= 1;
    int kk = u & 3; u >>= 2;
    int c = u & 3; u >>= 2;
    int l = u;
    int col = wc * 64 + nf * 16 + (lane & 15);
    int kbase = kk * 32 + (lane >> 4) * 8;
    size_t ob = ((((((size_t)(l * 4 + c) * 4 + kk) * 2 + wc) * 4 + nf) * 2) * 512) + lane * 8;
    unsigned short* dst = which == 0 ? W1p : W2p;
    #pragma unroll
    for (int j = 0; j < 8; j++){
        int k = kbase + j;
        float wv = which == 0 ? W1[((size_t)(l * 512) + c * 128 + col) * 128 + k]
                              : W2[((size_t)(l * 128) + col) * 512 + c * 128 + k];
        unsigned short hi = f2b(wv);
        unsigned short lo = f2b(wv - b2f(hi));
        dst[ob + j] = hi;
        dst[ob + 512 + j] = lo;
    }
}

// ------- GIN aggregation + bf16x2 split: 32 lanes/node, float4, 4-deep unroll -------
__global__ __launch_bounds__(256) void agg_split_kernel(
    const float* __restrict__ h, const int* __restrict__ row_ptr,
    const int* __restrict__ colv,
    unsigned short* __restrict__ zhi, unsigned short* __restrict__ zlo, int N)
{
    int t = blockIdx.x * 256 + threadIdx.x;
    int i = t >> 5;
    if (i >= N) return;
    int vo = (t & 31);
    const float4* hv = reinterpret_cast<const float4*>(h);
    int p0 = row_ptr[i], p1 = row_ptr[i + 1];
    float4 acc = hv[(size_t)i * 32 + vo];
    int p = p0;
    for (; p + 4 <= p1; p += 4){
        int s0 = colv[p], s1 = colv[p + 1], s2 = colv[p + 2], s3 = colv[p + 3];
        float4 a = hv[(size_t)s0 * 32 + vo];
        float4 b = hv[(size_t)s1 * 32 + vo];
        float4 c = hv[(size_t)s2 * 32 + vo];
        float4 d = hv[(size_t)s3 * 32 + vo];
        acc.x += (a.x + b.x) + (c.x + d.x);
        acc.y += (a.y + b.y) + (c.y + d.y);
        acc.z += (a.z + b.z) + (c.z + d.z);
        acc.w += (a.w + b.w) + (c.w + d.w);
    }
    for (; p < p1; p++){
        float4 a = hv[(size_t)colv[p] * 32 + vo];
        acc.x += a.x; acc.y += a.y; acc.z += a.z; acc.w += a.w;
    }
    float vals[4] = {acc.x, acc.y, acc.z, acc.w};
    unsigned int h01, h23, l01, l23;
    {
        unsigned short hh[4], ll[4];
        #pragma unroll
        for (int j = 0; j < 4; j++){
            hh[j] = f2b(vals[j]);
            ll[j] = f2b(vals[j] - b2f(hh[j]));
        }
        h01 = (unsigned int)hh[0] | ((unsigned int)hh[1] << 16);
        h23 = (unsigned int)hh[2] | ((unsigned int)hh[3] << 16);
        l01 = (unsigned int)ll[0] | ((unsigned int)ll[1] << 16);
        l23 = (unsigned int)ll[2] | ((unsigned int)ll[3] << 16);
    }
    uint2* ph = reinterpret_cast<uint2*>(zhi + (size_t)i * 128 + vo * 4);
    *ph = make_uint2(h01, h23);
    uint2* pl = reinterpret_cast<uint2*>(zlo + (size_t)i * 128 + vo * 4);
    *pl = make_uint2(l01, l23);
}

// -------- stats pass (8 waves): gemm1 MFMA, NO stores, BN sum/sq atomics --------
__global__ __launch_bounds__(512) void stats_k(
    const unsigned short* __restrict__ Ahi_g, const unsigned short* __restrict__ Alo_g,
    const unsigned short* __restrict__ Bp, float* __restrict__ bn_acc, int N)
{
    __shared__ __align__(16) unsigned short Ah[128][136];
    __shared__ __align__(16) unsigned short Al[128][136];
    int tid = threadIdx.x, lane = tid & 63, w = tid >> 6;
    int wr = w >> 2, wq = w & 3;
    int r_lo = lane & 15, kg = lane >> 4;
    int m0 = blockIdx.x * 128;

    {
        int r = tid >> 2, hf = tid & 3;
        int grow = m0 + r;
        #pragma unroll
        for (int j = 0; j < 4; j++){
            int kc = hf * 32 + j * 8;
            uint4 hvv = make_uint4(0, 0, 0, 0), lvv = make_uint4(0, 0, 0, 0);
            if (grow < N){
                hvv = *reinterpret_cast<const uint4*>(Ahi_g + (size_t)grow * 128 + kc);
                lvv = *reinterpret_cast<const uint4*>(Alo_g + (size_t)grow * 128 + kc);
            }
            *reinterpret_cast<uint4*>(&Ah[r][kc]) = hvv;
            *reinterpret_cast<uint4*>(&Al[r][kc]) = lvv;
        }
    }
    __syncthreads();

    int wc = wq >> 1;
    for (int c = 0; c < 4; c++){
        const bf16x8* Bv = reinterpret_cast<const bf16x8*>(Bp) + (size_t)c * 4096;
        f32x4 acc[4][2];
        #pragma unroll
        for (int i = 0; i < 4; i++)
            #pragma unroll
            for (int j = 0; j < 2; j++) acc[i][j] = (f32x4){0.f, 0.f, 0.f, 0.f};

        for (int kk = 0; kk < 4; kk++){
            bf16x8 bh[2], bl[2];
            #pragma unroll
            for (int nf = 0; nf < 2; nf++){
                int nfold = (wq & 1) * 2 + nf;
                int ob = ((kk * 2 + wc) * 4 + nfold) * 2;
                bh[nf] = Bv[(ob + 0) * 64 + lane];
                bl[nf] = Bv[(ob + 1) * 64 + lane];
            }
            bf16x8 ah[4], alr[4];
            #pragma unroll
            for (int mf = 0; mf < 4; mf++){
                int ar = wr * 64 + mf * 16 + r_lo;
                ah[mf]  = *reinterpret_cast<const bf16x8*>(&Ah[ar][kk * 32 + kg * 8]);
                alr[mf] = *reinterpret_cast<const bf16x8*>(&Al[ar][kk * 32 + kg * 8]);
            }
            #pragma unroll
            for (int mf = 0; mf < 4; mf++)
                #pragma unroll
                for (int nf = 0; nf < 2; nf++){
                    acc[mf][nf] = __builtin_amdgcn_mfma_f32_16x16x32_bf16(ah[mf],  bh[nf], acc[mf][nf], 0, 0, 0);
                    acc[mf][nf] = __builtin_amdgcn_mfma_f32_16x16x32_bf16(ah[mf],  bl[nf], acc[mf][nf], 0, 0, 0);
                    acc[mf][nf] = __builtin_amdgcn_mfma_f32_16x16x32_bf16(alr[mf], bh[nf], acc[mf][nf], 0, 0, 0);
                }
        }

        #pragma unroll
        for (int nf = 0; nf < 2; nf++){
            int col = wq * 32 + nf * 16 + r_lo;
            float s = 0.f, q = 0.f;
            #pragma unroll
            for (int mf = 0; mf < 4; mf++)
                #pragma unroll
                for (int r = 0; r < 4; r++){
                    int row = m0 + wr * 64 + mf * 16 + kg * 4 + r;
                    if (row < N){
                        float v = acc[mf][nf][r];
                        s += v; q += v * v;
                    }
                }
            s += __shfl_xor(s, 16); s += __shfl_xor(s, 32);
            q += __shfl_xor(q, 16); q += __shfl_xor(q, 32);
            if (lane < 16){
                atomicAdd(&bn_acc[c * 256 + col], s);
                atomicAdd(&bn_acc[c * 256 + 128 + col], q);
            }
        }
    }
}

// ------- BN finalize: all 512 cols -------
__global__ void bn_final_k(const float* __restrict__ bn_acc,
                           const float* __restrict__ bng, const float* __restrict__ bnb,
                           float* __restrict__ sc, float* __restrict__ sh,
                           int l, float invN){
    int colg = threadIdx.x;   // 512 threads
    float s = bn_acc[(colg >> 7) * 256 + (colg & 127)];
    float q = bn_acc[(colg >> 7) * 256 + 128 + (colg & 127)];
    float mu = s * invN;
    float var = q * invN - mu * mu;
    float inv = rsqrtf(var + 1e-5f);
    float g = bng[l * 512 + colg] * inv;
    sc[colg] = g;
    sh[colg] = bnb[l * 512 + colg] - mu * g;
}

// ------- fused (8 waves): recompute z1 chunk -> BN+SELU+split -> LDS -> gemm2 -> z2 -------
__global__ __launch_bounds__(512, 1) void fused_k(
    const unsigned short* __restrict__ Ahi_g, const unsigned short* __restrict__ Alo_g,
    const unsigned short* __restrict__ B1p, const unsigned short* __restrict__ B2p,
    float* __restrict__ Z, const float* __restrict__ bsc, const float* __restrict__ bsh,
    const float* __restrict__ b2l, int N)
{
    __shared__ __align__(16) unsigned short Ah[128][136];
    __shared__ __align__(16) unsigned short Al[128][136];
    __shared__ __align__(16) unsigned short Ph[128][136];
    __shared__ __align__(16) unsigned short Pl[128][136];
    __shared__ float s_sc[512], s_sh[512];
    int tid = threadIdx.x, lane = tid & 63, w = tid >> 6;
    int wr = w >> 2, wq = w & 3;
    int r_lo = lane & 15, kg = lane >> 4;
    int m0 = blockIdx.x * 128;

    if (tid < 512){ s_sc[tid] = bsc[tid]; s_sh[tid] = bsh[tid]; }
    {
        int r = tid >> 2, hf = tid & 3;
        int grow = m0 + r;
        #pragma unroll
        for (int j = 0; j < 4; j++){
            int kc = hf * 32 + j * 8;
            uint4 hvv = make_uint4(0, 0, 0, 0), lvv = make_uint4(0, 0, 0, 0);
            if (grow < N){
                hvv = *reinterpret_cast<const uint4*>(Ahi_g + (size_t)grow * 128 + kc);
                lvv = *reinterpret_cast<const uint4*>(Alo_g + (size_t)grow * 128 + kc);
            }
            *reinterpret_cast<uint4*>(&Ah[r][kc]) = hvv;
            *reinterpret_cast<uint4*>(&Al[r][kc]) = lvv;
        }
    }
    __syncthreads();

    int wc = wq >> 1;
    f32x4 acc2[4][2];
    #pragma unroll
    for (int i = 0; i < 4; i++)
        #pragma unroll
        for (int j = 0; j < 2; j++) acc2[i][j] = (f32x4){0.f, 0.f, 0.f, 0.f};

    for (int c = 0; c < 4; c++){
        // ---- gemm1 chunk: z1_c in registers ----
        f32x4 acc1[4][2];
        #pragma unroll
        for (int i = 0; i < 4; i++)
            #pragma unroll
            for (int j = 0; j < 2; j++) acc1[i][j] = (f32x4){0.f, 0.f, 0.f, 0.f};

        const bf16x8* B1v = reinterpret_cast<const bf16x8*>(B1p) + (size_t)c * 4096;
        for (int kk = 0; kk < 4; kk++){
            bf16x8 bh[2], bl[2];
            #pragma unroll
            for (int nf = 0; nf < 2; nf++){
                int nfold = (wq & 1) * 2 + nf;
                int ob = ((kk * 2 + wc) * 4 + nfold) * 2;
                bh[nf] = B1v[(ob + 0) * 64 + lane];
                bl[nf] = B1v[(ob + 1) * 64 + lane];
            }
            bf16x8 ah[4], alr[4];
            #pragma unroll
            for (int mf = 0; mf < 4; mf++){
                int ar = wr * 64 + mf * 16 + r_lo;
                ah[mf]  = *reinterpret_cast<const bf16x8*>(&Ah[ar][kk * 32 + kg * 8]);
                alr[mf] = *reinterpret_cast<const bf16x8*>(&Al[ar][kk * 32 + kg * 8]);
            }
            #pragma unroll
            for (int mf = 0; mf < 4; mf++)
                #pragma unroll
                for (int nf = 0; nf < 2; nf++){
                    acc1[mf][nf] = __builtin_amdgcn_mfma_f32_16x16x32_bf16(ah[mf],  bh[nf], acc1[mf][nf], 0, 0, 0);
                    acc1[mf][nf] = __builtin_amdgcn_mfma_f32_16x16x32_bf16(ah[mf],  bl[nf], acc1[mf][nf], 0, 0, 0);
                    acc1[mf][nf] = __builtin_amdgcn_mfma_f32_16x16x32_bf16(alr[mf], bh[nf], acc1[mf][nf], 0, 0, 0);
                }
        }

        // ---- BN + SELU + split -> Ph/Pl ----
        __syncthreads();
        #pragma unroll
        for (int nf = 0; nf < 2; nf++){
            int colk = wq * 32 + nf * 16 + r_lo;
            float scv = s_sc[c * 128 + colk], shv = s_sh[c * 128 + colk];
            #pragma unroll
            for (int mf = 0; mf < 4; mf++)
                #pragma unroll
                for (int r = 0; r < 4; r++){
                    int rl = wr * 64 + mf * 16 + kg * 4 + r;
                    float t = selu_f(fmaf(acc1[mf][nf][r], scv, shv));
                    unsigned short hi = f2b(t);
                    Ph[rl][colk] = hi;
                    Pl[rl][colk] = f2b(t - b2f(hi));
                }
        }
        __syncthreads();

        // ---- gemm2 accumulate over this K slice ----
        const bf16x8* B2v = reinterpret_cast<const bf16x8*>(B2p);
        for (int kk2 = 0; kk2 < 4; kk2++){
            int kkf = c * 4 + kk2;
            bf16x8 bh[2], bl[2];
            #pragma unroll
            for (int nf = 0; nf < 2; nf++){
                int nfold = (wq & 1) * 2 + nf;
                int ob = ((kkf * 2 + wc) * 4 + nfold) * 2;
                bh[nf] = B2v[(ob + 0) * 64 + lane];
                bl[nf] = B2v[(ob + 1) * 64 + lane];
            }
            bf16x8 ah[4], alr[4];
            #pragma unroll
            for (int mf = 0; mf < 4; mf++){
                int ar = wr * 64 + mf * 16 + r_lo;
                ah[mf]  = *reinterpret_cast<const bf16x8*>(&Ph[ar][kk2 * 32 + kg * 8]);
                alr[mf] = *reinterpret_cast<const bf16x8*>(&Pl[ar][kk2 * 32 + kg * 8]);
            }
            #pragma unroll
            for (int mf = 0; mf < 4; mf++)
                #pragma unroll
                for (int nf = 0; nf < 2; nf++){
                    acc2[mf][nf] = __builtin_amdgcn_mfma_f32_16x16x32_bf16(ah[mf],  bh[nf], acc2[mf][nf], 0, 0, 0);
                    acc2[mf][nf] = __builtin_amdgcn_mfma_f32_16x16x32_bf16(ah[mf],  bl[nf], acc2[mf][nf], 0, 0, 0);
                    acc2[mf][nf] = __builtin_amdgcn_mfma_f32_16x16x32_bf16(alr[mf], bh[nf], acc2[mf][nf], 0, 0, 0);
                }
        }
    }

    // ---- write z2 = acc2 + b2 ----
    #pragma unroll
    for (int nf = 0; nf < 2; nf++){
        int col = wq * 32 + nf * 16 + r_lo;
        float bv = b2l[col];
        #pragma unroll
        for (int mf = 0; mf < 4; mf++)
            #pragma unroll
            for (int r = 0; r < 4; r++){
                int row = m0 + wr * 64 + mf * 16 + kg * 4 + r;
                if (row < N)
                    Z[(size_t)row * 128 + col] = bv + acc2[mf][nf][r];
            }
    }
}

// ---------------- GraphNorm stats: float4 x 16-row slabs ----------------
__global__ __launch_bounds__(256) void gn_stats_kernel(
    const float* __restrict__ z2, const int* __restrict__ batch,
    float* __restrict__ gsum, float* __restrict__ gsq, int N)
{
    __shared__ int sb[128];
    int tid = threadIdx.x;
    int base = blockIdx.x * 128;
    int end = min(128, N - base);
    if (tid < 128) sb[tid] = (tid < end) ? batch[base + tid] : 0;
    __syncthreads();
    int vo = tid & 31;
    int r0 = (tid >> 5) * 16;
    if (r0 >= end) return;
    int rend = min(r0 + 16, end);
    const float4* zv = reinterpret_cast<const float4*>(z2);
    float sx = 0.f, sy = 0.f, sz = 0.f, sw = 0.f;
    float qx = 0.f, qy = 0.f, qz = 0.f, qw = 0.f;
    int run_g = sb[r0];
    for (int r = r0; r < rend; r++){
        int g = sb[r];
        if (g != run_g){
            float* gs = &gsum[run_g * 128 + vo * 4];
            float* gq = &gsq[run_g * 128 + vo * 4];
            atomicAdd(gs + 0, sx); atomicAdd(gs + 1, sy); atomicAdd(gs + 2, sz); atomicAdd(gs + 3, sw);
            atomicAdd(gq + 0, qx); atomicAdd(gq + 1, qy); atomicAdd(gq + 2, qz); atomicAdd(gq + 3, qw);
            sx = sy = sz = sw = 0.f; qx = qy = qz = qw = 0.f;
            run_g = g;
        }
        float4 v = zv[(size_t)(base + r) * 32 + vo];
        sx += v.x; sy += v.y; sz += v.z; sw += v.w;
        qx += v.x * v.x; qy += v.y * v.y; qz += v.z * v.z; qw += v.w * v.w;
    }
    float* gs = &gsum[run_g * 128 + vo * 4];
    float* gq = &gsq[run_g * 128 + vo * 4];
    atomicAdd(gs + 0, sx); atomicAdd(gs + 1, sy); atomicAdd(gs + 2, sz); atomicAdd(gs + 3, sw);
    atomicAdd(gq + 0, qx); atomicAdd(gq + 1, qy); atomicAdd(gq + 2, qz); atomicAdd(gq + 3, qw);
}

__global__ void gn_final_kernel(float* __restrict__ gsum, float* __restrict__ gsq,
                                const float* __restrict__ cnt,
                                const float* __restrict__ gng, const float* __restrict__ gnb,
                                const float* __restrict__ gna,
                                float* __restrict__ scale, float* __restrict__ shift, int l){
    int g = blockIdx.x, c = threadIdx.x;
    int idx = g * 128 + c;
    float n = cnt[g];
    float m = gsum[idx] / n;
    float e2 = gsq[idx] / n;
    float a = gna[l * 128 + c];
    float var = e2 - (2.f * a - a * a) * m * m;
    float inv = rsqrtf(var + 1e-5f);
    float sc = gng[l * 128 + c] * inv;
    scale[idx] = sc;
    shift[idx] = gnb[l * 128 + c] - a * m * sc;
    gsum[idx] = 0.f;
    gsq[idx] = 0.f;
}

// ------- apply GraphNorm + SELU in place (z2 -> h), pool: float4 slabs -------
__global__ __launch_bounds__(256) void gn_apply_kernel(
    float* __restrict__ z2h, const int* __restrict__ batch,
    const float* __restrict__ scale, const float* __restrict__ shift,
    float* __restrict__ pool, int l, int N)
{
    __shared__ int sb[128];
    int tid = threadIdx.x;
    int base = blockIdx.x * 128;
    int end = min(128, N - base);
    if (tid < 128) sb[tid] = (tid < end) ? batch[base + tid] : 0;
    __syncthreads();
    int vo = tid & 31;
    int r0 = (tid >> 5) * 16;
    if (r0 >= end) return;
    int rend = min(r0 + 16, end);
    float4* zv = reinterpret_cast<float4*>(z2h);
    int run_g = sb[r0];
    float scx = scale[run_g * 128 + vo * 4 + 0], shx = shift[run_g * 128 + vo * 4 + 0];
    float scy = scale[run_g * 128 + vo * 4 + 1], shy = shift[run_g * 128 + vo * 4 + 1];
    float scz = scale[run_g * 128 + vo * 4 + 2], shz = shift[run_g * 128 + vo * 4 + 2];
    float scw = scale[run_g * 128 + vo * 4 + 3], shw = shift[run_g * 128 + vo * 4 + 3];
    float px = 0.f, py = 0.f, pz = 0.f, pw = 0.f;
    for (int r = r0; r < rend; r++){
        int g = sb[r];
        if (g != run_g){
            float* pp = &pool[run_g * 512 + l * 128 + vo * 4];
            atomicAdd(pp + 0, px); atomicAdd(pp + 1, py); atomicAdd(pp + 2, pz); atomicAdd(pp + 3, pw);
            px = py = pz = pw = 0.f;
            run_g = g;
            scx = scale[g * 128 + vo * 4 + 0]; shx = shift[g * 128 + vo * 4 + 0];
            scy = scale[g * 128 + vo * 4 + 1]; shy = shift[g * 128 + vo * 4 + 1];
            scz = scale[g * 128 + vo * 4 + 2]; shz = shift[g * 128 + vo * 4 + 2];
            scw = scale[g * 128 + vo * 4 + 3]; shw = shift[g * 128 + vo * 4 + 3];
        }
        size_t idx = (size_t)(base + r) * 32 + vo;
        float4 v = zv[idx];
        v.x = selu_f(fmaf(v.x, scx, shx));
        v.y = selu_f(fmaf(v.y, scy, shy));
        v.z = selu_f(fmaf(v.z, scz, shz));
        v.w = selu_f(fmaf(v.w, scw, shw));
        zv[idx] = v;
        px += v.x; py += v.y; pz += v.z; pw += v.w;
    }
    float* pp = &pool[run_g * 512 + l * 128 + vo * 4];
    atomicAdd(pp + 0, px); atomicAdd(pp + 1, py); atomicAdd(pp + 2, pz); atomicAdd(pp + 3, pw);
}

__global__ void final_kernel(const float* __restrict__ pool, const float* __restrict__ cnt,
                             float* __restrict__ out, int n){
    int i = blockIdx.x * 256 + threadIdx.x;
    if (i < n) out[i] = pool[i] / cnt[i >> 9];
}

extern "C" void kernel_launch(void* const* d_in, const int* in_sizes, int n_in,
                              void* d_out, int out_size, void* d_ws, size_t ws_size,
                              hipStream_t stream){
    const float* x    = (const float*)d_in[0];
    const float* W1   = (const float*)d_in[1];
    const float* bng  = (const float*)d_in[2];
    const float* bnb  = (const float*)d_in[3];
    const float* W2   = (const float*)d_in[4];
    const float* b2   = (const float*)d_in[5];
    const float* gng  = (const float*)d_in[6];
    const float* gnb  = (const float*)d_in[7];
    const float* gna  = (const float*)d_in[8];
    const int*   ei   = (const int*)d_in[9];
    const int*   batch= (const int*)d_in[10];
    int N = in_sizes[0] / 128;
    int E = in_sizes[9] / 2;
    float* out = (float*)d_out;
    int RB = (N + 127) / 128;

    char* ws = (char*)d_ws;
    size_t off = 0;
    auto alloc = [&](size_t bytes) -> char* {
        char* p = ws + off;
        off += (bytes + 255) & ~(size_t)255;
        return p;
    };
    unsigned short* z0hi = (unsigned short*)alloc((size_t)N * 128 * 2);
    unsigned short* z0lo = (unsigned short*)alloc((size_t)N * 128 * 2);
    float* z2     = (float*)alloc((size_t)N * 128 * 4);   // doubles as h
    unsigned short* W1p = (unsigned short*)alloc(524288 * 2);
    unsigned short* W2p = (unsigned short*)alloc(524288 * 2);
    int*   row_ptr= (int*)alloc((size_t)(N + 1) * 4);
    int*   colv   = (int*)alloc((size_t)E * 4);
    int*   counts = (int*)alloc((size_t)N * 4);
    int*   fill   = (int*)alloc((size_t)N * 4);
    float* cnt_f  = (float*)alloc(256 * 4);
    float* bn_acc = (float*)alloc(16 * 256 * 4);   // [l*4+c][sum 128 | sq 128]
    float* bn_sc  = (float*)alloc(512 * 4);
    float* bn_sh  = (float*)alloc(512 * 4);
    float* gn_sum = (float*)alloc(256 * 128 * 4);  // contiguous with gn_sq
    float* gn_sq  = (float*)alloc(256 * 128 * 4);
    float* gn_sc  = (float*)alloc(256 * 128 * 4);
    float* gn_sh  = (float*)alloc(256 * 128 * 4);
    float* pool   = (float*)alloc(256 * 512 * 4);
    (void)ws_size;

    hipMemsetAsync(counts, 0, (size_t)N * 4, stream);
    hipMemsetAsync(fill,   0, (size_t)N * 4, stream);
    hipMemsetAsync(bn_acc, 0, 16 * 256 * 4, stream);
    hipMemsetAsync(gn_sum, 0, 2 * 256 * 128 * 4, stream);      // gn_sum + gn_sq
    hipMemsetAsync(pool,   0, 256 * 512 * 4, stream);

    pack_kernel<<<256, 256, 0, stream>>>(W1, W2, W1p, W2p);
    count_kernel<<<(E + 255) / 256, 256, 0, stream>>>(ei + E, counts, E);
    scan_kernel<<<1, 1024, 0, stream>>>(counts, row_ptr, N);
    fill_kernel<<<(E + 255) / 256, 256, 0, stream>>>(ei, row_ptr, fill, colv, E);
    cnt_bs_kernel<<<1, 256, 0, stream>>>(batch, cnt_f, N);

    const float* hcur = x;
    float invN = 1.f / (float)N;
    for (int l = 0; l < 4; l++){
        agg_split_kernel<<<(N + 7) / 8, 256, 0, stream>>>(hcur, row_ptr, colv, z0hi, z0lo, N);
        stats_k<<<RB, 512, 0, stream>>>(z0hi, z0lo, W1p + (size_t)l * 131072,
                                        bn_acc + l * 1024, N);
        bn_final_k<<<1, 512, 0, stream>>>(bn_acc + l * 1024, bng, bnb,
                                          bn_sc, bn_sh, l, invN);
        fused_k<<<RB, 512, 0, stream>>>(z0hi, z0lo, W1p + (size_t)l * 131072,
                                        W2p + (size_t)l * 131072, z2,
                                        bn_sc, bn_sh, b2 + l * 128, N);
        gn_stats_kernel<<<RB, 256, 0, stream>>>(z2, batch, gn_sum, gn_sq, N);
        gn_final_kernel<<<256, 128, 0, stream>>>(gn_sum, gn_sq, cnt_f, gng, gnb, gna,
                                                 gn_sc, gn_sh, l);
        gn_apply_kernel<<<RB, 256, 0, stream>>>(z2, batch, gn_sc, gn_sh, pool, l, N);
        hcur = z2;
    }
    final_kernel<<<(out_size + 255) / 256, 256, 0, stream>>>(pool, cnt_f, out, out_size);
}